// Round 4
// baseline (1019.749 us; speedup 1.0000x reference)
//
#include <hip/hip_runtime.h>

// ---------------------------------------------------------------------------
// GLA_GCN bf16-MFMA pipeline. B=4096, J=25, D_IN=512, D_H=256, D_OUT=512.
// Partition 1 is dead (all its joints overwritten by parts 2/3/4).
// GEMMs are GROUPED: one dispatch for all five "a" GEMMs (672 wg), one for
// all five "b" GEMMs (1344 wg), plus Wf0/Wf1 (800 wg each).
// GEMM inner loop: 256x256 tile, BK=64, 8 waves, 4-phase/iter schedule
// (2 K-tiles per iter, 32 MFMA per phase), counted vmcnt(4) at P1/P3
// (vmcnt(0) only at last-iter P1), 2dbuf x {A,B} 32 KiB K-tile slabs
// (128 KiB LDS), chunk-XOR swizzle (bank-conflict-free ds_read_b128),
// m201 pinning discipline (lgkmcnt(8) hint, sched_barrier+s_barrier+
// lgkmcnt(0)+sched_barrier, setprio around MFMA), XCD block swizzle.
// XG|XL stored interleaved per row (XGL, lda=1024) so fusion GEMM is plain.
// ---------------------------------------------------------------------------

#define BATCH 4096
#define NJOINT 25
#define MROWS (BATCH * NJOINT)          // 102400
#define SZ_FULL (MROWS * 512)           // 52,428,800 bf16 elements

typedef __attribute__((ext_vector_type(8))) short short8;
typedef __attribute__((ext_vector_type(4))) float float4_;

__device__ __forceinline__ float b2f(ushort u) {
    union { float f; uint32_t i; } x; x.i = ((uint32_t)u) << 16; return x.f;
}
__device__ __forceinline__ ushort f2b(float f) {
    union { float f; uint32_t i; } x; x.f = f;
    uint32_t r = x.i + 0x7fff + ((x.i >> 16) & 1);
    return (ushort)(r >> 16);
}
__device__ __forceinline__ void async16(const void* g, void* l) {
    __builtin_amdgcn_global_load_lds(
        (const __attribute__((address_space(1))) void*)g,
        (__attribute__((address_space(3))) void*)l, 16, 0, 0);
}

// ---------------------------------------------------------------------------
// Adjacency normalization (fp32, tiny)
// ---------------------------------------------------------------------------
__device__ void norm_one(const float* A, int n, float* out, float* sAdj, float* sD) {
    int t = threadIdx.x;
    for (int i = t; i < n * n; i += 256) sAdj[i] = A[i];
    __syncthreads();
    if (t < n) {
        float s = 0.f;
        for (int j = 0; j < n; j++) s += sAdj[t * n + j];
        sD[t] = 1.0f / sqrtf(fmaxf(s, 1e-6f));
    }
    __syncthreads();
    for (int i = t; i < n * n; i += 256) {
        int r = i / n, c = i % n;
        out[i] = sD[r] * sAdj[i] * sD[c];
    }
    __syncthreads();
}

__global__ __launch_bounds__(256) void adjnorm_kernel(
    const float* Ag, const float* A0, const float* A2, const float* A3,
    const float* A4, float* ADJ) {
    __shared__ float sAdj[640];
    __shared__ float sD[32];
    norm_one(Ag, 25, ADJ, sAdj, sD);
    norm_one(A0, 5, ADJ + 640 + 0 * 64, sAdj, sD);
    norm_one(A2, 3, ADJ + 640 + 1 * 64, sAdj, sD);
    norm_one(A3, 3, ADJ + 640 + 2 * 64, sAdj, sD);
    norm_one(A4, 6, ADJ + 640 + 3 * 64, sAdj, sD);
}

// ---------------------------------------------------------------------------
// fp32 -> bf16 convert (x), float4 -> ushort4
// ---------------------------------------------------------------------------
__global__ __launch_bounds__(256) void cvt_bf16(const float* __restrict__ in,
                                                ushort* __restrict__ out, int n4) {
    int id = blockIdx.x * 256 + threadIdx.x;
    if (id < n4) {
        float4 v = ((const float4*)in)[id];
        ushort4 o;
        o.x = f2b(v.x); o.y = f2b(v.y); o.z = f2b(v.z); o.w = f2b(v.w);
        ((ushort4*)out)[id] = o;
    }
}

// ---------------------------------------------------------------------------
// Grouped weight transpose: W fp32 [K][N] -> Wt bf16 [N][K], 12 regions.
// ---------------------------------------------------------------------------
struct WDesc { const float* W; ushort* Wt; int K, N, nxlog, end; };
struct WParams { WDesc d[12]; };

__global__ __launch_bounds__(256) void wtrans_all(WParams P) {
    __shared__ float tile[32][33];
    int bid = blockIdx.x;
    int i = 0, start = 0;
    while (bid >= P.d[i].end) { start = P.d[i].end; i++; }
    const WDesc& D = P.d[i];
    int local = bid - start;
    int bx = local & ((1 << D.nxlog) - 1);
    int by = local >> D.nxlog;
    int K = D.K, N = D.N;
    int t = threadIdx.x, tx = t & 31, ty = t >> 5;
    int k0 = by * 32, n0 = bx * 32;
    for (int r = ty; r < 32; r += 8)
        tile[r][tx] = D.W[(size_t)(k0 + r) * N + n0 + tx];
    __syncthreads();
    for (int r = ty; r < 32; r += 8)
        D.Wt[(size_t)(n0 + r) * K + k0 + tx] = f2b(tile[tx][r]);
}

// ---------------------------------------------------------------------------
// Zero XL joints 17..24 in XGL interleaved layout (row stride 1024, XL at +512)
// ---------------------------------------------------------------------------
__global__ __launch_bounds__(256) void zero_tail(ushort* __restrict__ XGL) {
    int id = blockIdx.x * 256 + threadIdx.x;
    int f4 = id & 127;
    int rj = (id >> 7) & 7;
    int b = id >> 10;
    ushort4 z; z.x = 0; z.y = 0; z.z = 0; z.w = 0;
    ((ushort4*)(XGL + ((size_t)(b * 25 + 17 + rj) * 1024 + 512)))[f4] = z;
}

// ---------------------------------------------------------------------------
// Grouped bf16 MFMA GEMM, 4-phase/iter schedule. Up to 5 groups per dispatch.
//   Per group: C[M,N] = act(A @ Wt^T [+ bias]); A row-major (lda),
//   Wt [N][K], C (ldc). flags: 1=GATHER, 2=BIAS, 4=RELU, 8=OUTF32.
//   256x256 tile, BK=64, 8 waves (2Mx4N), per-wave 128x64 via 8x4x2 of
//   mfma_f32_16x16x32_bf16. LDS: 2 dbuf x {A 32K, B 32K} K-tile slabs.
//   One iteration = 2 K-tiles = 4 phases; each phase computes one fi-half
//   (4 fi x 4 fj x 2 kk = 32 MFMA) and stages one full K-tile slab
//   (4 x global_load_lds per thread).
//   Stage stream (iter j): P0: A(2j+1)->d1; P1: B(2j+2)->d0;
//   P2: A(2j+2)->d0; P3: B(2j+3)->d1.
//   vmcnt(4) at P1 (completes prevP3.B + P0.A -> d1 ready for P2) and at
//   P3 (completes P1.B + P2.A -> d0 ready for next P0); last-iter P1 uses
//   vmcnt(0). Every wait is barrier-separated from the first read of the
//   data it covers -> cross-wave safety transitive through phase barriers.
//   Swizzle: rows of 8 x 16B chunks; linear LDS dest, source chunk =
//   lanechunk ^ (row&7), read chunk = (q or q^4) ^ (row&7) => conflict-free.
// ---------------------------------------------------------------------------
struct GDesc {
    const ushort* A; const ushort* Wt; const float* bias; void* C;
    int K, lda, ldc, nTiles, wgEnd, gn, flags, pad;
    int gmap[6];
};
struct GParams { GDesc g[5]; };

__global__ __launch_bounds__(512, 2) void gemmg(GParams P) {
    __shared__ ushort lds[65536];   // 128 KiB: [2 dbuf][A 8192|B 8192 rows]
    int t = threadIdx.x;
    int l = t & 63, w = t >> 6;

    // bijective XCD swizzle (all grids are multiples of 8)
    int nwg = (int)gridDim.x;
    int cpx = nwg >> 3;
    int wg = ((int)blockIdx.x & 7) * cpx + ((int)blockIdx.x >> 3);

    int gi = 0, wg0 = 0;
    while (wg >= P.g[gi].wgEnd) { wg0 = P.g[gi].wgEnd; gi++; }
    const GDesc& G = P.g[gi];
    int lw = wg - wg0;
    int tm, tn;
    if (G.nTiles == 2) { tm = lw >> 1; tn = lw & 1; }
    else               { tm = lw;      tn = 0; }
    int bm = tm << 8, bn = tn << 8;
    const int K = G.K, lda = G.lda, ldc = G.ldc;
    const bool GATHER = (G.flags & 1) != 0;
    const bool BIAS   = (G.flags & 2) != 0;
    const bool RELU   = (G.flags & 4) != 0;
    const bool OUTF32 = (G.flags & 8) != 0;

    // staging: lane l covers row (l>>3), linear chunk (l&7); source chunk
    // pre-swizzled by ^(row&7) = ^(l>>3)
    int srow = (w << 4) + (l >> 3);
    int sch = ((l & 7) ^ (l >> 3)) << 3;
    const ushort* pA[2][2];
    const ushort* pB[2][2];
#pragma unroll
    for (int h = 0; h < 2; h++)
#pragma unroll
        for (int i = 0; i < 2; i++) {
            int r = bm + h * 128 + srow + i * 8;
            if (GATHER) { int b = r / G.gn; r = b * 25 + G.gmap[r - b * G.gn]; }
            pA[h][i] = G.A + (size_t)r * lda + sch;
            int c = bn + h * 128 + srow + i * 8;
            pB[h][i] = G.Wt + (size_t)c * K + sch;
        }
    int stga = w << 10;

    // fragment read offsets
    int wm = w >> 2, wn = w & 3;
    int lr = l & 15, q = l >> 4;
    int cx = lr & 7;
    int ca0 = (q ^ cx) << 3;
    int ca1 = ca0 ^ 32;
    int ra = (wm << 13) + (lr << 6);
    int rb = 16384 + ((wn >> 1) << 13) + ((wn & 1) << 12) + (lr << 6);

    float4_ acc[8][4];
#pragma unroll
    for (int fi = 0; fi < 8; fi++)
#pragma unroll
        for (int fj = 0; fj < 4; fj++) acc[fi][fj] = (float4_)0.f;
    short8 bfr[4][2];

#define STG_AT(DB, KT) do {                                                \
        async16(pA[0][0] + (KT) * 64, &lds[(DB) + stga]);                  \
        async16(pA[0][1] + (KT) * 64, &lds[(DB) + stga + 512]);            \
        async16(pA[1][0] + (KT) * 64, &lds[(DB) + 8192 + stga]);           \
        async16(pA[1][1] + (KT) * 64, &lds[(DB) + 8192 + stga + 512]);     \
    } while (0)
#define STG_BT(DB, KT) do {                                                \
        async16(pB[0][0] + (KT) * 64, &lds[(DB) + 16384 + stga]);          \
        async16(pB[0][1] + (KT) * 64, &lds[(DB) + 16384 + stga + 512]);    \
        async16(pB[1][0] + (KT) * 64, &lds[(DB) + 24576 + stga]);          \
        async16(pB[1][1] + (KT) * 64, &lds[(DB) + 24576 + stga + 512]);    \
    } while (0)

#define DO_PHASE(DB, FI0, RDB, WAITST, STMT) do {                          \
        short8 af[4][2];                                                   \
        if (RDB) {                                                         \
            _Pragma("unroll")                                              \
            for (int fj = 0; fj < 4; fj++) {                               \
                bfr[fj][0] = *(const short8*)&lds[(DB) + rb + fj * 1024 + ca0]; \
                bfr[fj][1] = *(const short8*)&lds[(DB) + rb + fj * 1024 + ca1]; \
            }                                                              \
        }                                                                  \
        _Pragma("unroll")                                                  \
        for (int fi = 0; fi < 4; fi++) {                                   \
            af[fi][0] = *(const short8*)&lds[(DB) + ra + ((FI0) + fi) * 1024 + ca0]; \
            af[fi][1] = *(const short8*)&lds[(DB) + ra + ((FI0) + fi) * 1024 + ca1]; \
        }                                                                  \
        STMT                                                               \
        WAITST                                                             \
        if (RDB) asm volatile("s_waitcnt lgkmcnt(8)");                     \
        __builtin_amdgcn_sched_barrier(0);                                 \
        __builtin_amdgcn_s_barrier();                                      \
        asm volatile("s_waitcnt lgkmcnt(0)" ::: "memory");                 \
        __builtin_amdgcn_sched_barrier(0);                                 \
        __builtin_amdgcn_s_setprio(1);                                     \
        _Pragma("unroll")                                                  \
        for (int kk = 0; kk < 2; kk++)                                     \
            _Pragma("unroll")                                              \
            for (int fi = 0; fi < 4; fi++)                                 \
                _Pragma("unroll")                                          \
                for (int fj = 0; fj < 4; fj++)                             \
                    acc[(FI0) + fi][fj] = __builtin_amdgcn_mfma_f32_16x16x32_bf16( \
                        af[fi][kk], bfr[fj][kk], acc[(FI0) + fi][fj], 0, 0, 0); \
        __builtin_amdgcn_s_setprio(0);                                     \
        __builtin_amdgcn_sched_barrier(0);                                 \
        __builtin_amdgcn_s_barrier();                                      \
    } while (0)

    int NT = K >> 6;              // K-tiles of 64 (NT even, >= 4 here)
    int NITER = NT >> 1;

    // prologue: kt0 (A+B) -> d0, kt1.B -> d1; wait for kt0, barrier.
    STG_AT(0, 0);
    STG_BT(0, 0);
    STG_BT(32768, 1);
    asm volatile("s_waitcnt vmcnt(4)" ::: "memory");
    __builtin_amdgcn_sched_barrier(0);
    __builtin_amdgcn_s_barrier();

    for (int j = 0; j < NITER; ++j) {
        int k1 = 2 * j + 1, k2 = 2 * j + 2, k3 = 2 * j + 3;
        bool nl = (j + 1 < NITER);
        DO_PHASE(0, 0, true, , STG_AT(32768, k1););
        DO_PHASE(0, 4, false,
                 if (nl) { asm volatile("s_waitcnt vmcnt(4)" ::: "memory"); }
                 else    { asm volatile("s_waitcnt vmcnt(0)" ::: "memory"); },
                 if (nl) STG_BT(0, k2););
        DO_PHASE(32768, 0, true, , if (nl) STG_AT(0, k2););
        DO_PHASE(32768, 4, false,
                 if (nl) { asm volatile("s_waitcnt vmcnt(4)" ::: "memory"); },
                 if (nl) STG_BT(32768, k3););
    }
#undef DO_PHASE
#undef STG_AT
#undef STG_BT

    // epilogue: C/D layout col=lane&15, row=(lane>>4)*4+reg
    int cl = lr;
    float bv[4];
#pragma unroll
    for (int fj = 0; fj < 4; fj++)
        bv[fj] = BIAS ? G.bias[bn + (wn << 6) + (fj << 4) + cl] : 0.f;
#pragma unroll
    for (int fi = 0; fi < 8; fi++) {
        int row0 = bm + (wm << 7) + (fi << 4) + (q << 2);
#pragma unroll
        for (int r = 0; r < 4; r++) {
            size_t rowoff = (size_t)(row0 + r) * ldc;
#pragma unroll
            for (int fj = 0; fj < 4; fj++) {
                int col = bn + (wn << 6) + (fj << 4) + cl;
                float v = acc[fi][fj][r] + bv[fj];
                if (RELU) v = fmaxf(v, 0.f);
                if (OUTF32)
                    ((float*)G.C)[rowoff + col] = v;
                else
                    ((ushort*)G.C)[rowoff + col] = f2b(v);
            }
        }
    }
}

// ---------------------------------------------------------------------------
// Grouped mix pass 1 (F=256): T[b,i,f] = relu(sum_j adj[i,j]*T[b,j,f]+bias[f])
// 5 regions x 4096 blocks.
// ---------------------------------------------------------------------------
struct M1Desc { ushort* T; const float* adj; const float* bias; int nj; };
struct M1Params { M1Desc d[5]; };

template <int NJ>
__device__ __forceinline__ void mix1_body(ushort* base, const float* As, float bi) {
    float v[NJ];
#pragma unroll
    for (int j = 0; j < NJ; j++) v[j] = b2f(base[(size_t)j * 256]);
#pragma unroll
    for (int i = 0; i < NJ; i++) {
        float o = 0.f;
#pragma unroll
        for (int j = 0; j < NJ; j++) o += As[i * NJ + j] * v[j];
        base[(size_t)i * 256] = f2b(fmaxf(o + bi, 0.f));
    }
}

__global__ __launch_bounds__(256) void mixg1(M1Params P) {
    __shared__ float As[625];
    int r = blockIdx.x >> 12;
    const M1Desc& D = P.d[r];
    int t = threadIdx.x;
    int nj = D.nj;
    for (int i = t; i < nj * nj; i += 256) As[i] = D.adj[i];
    __syncthreads();
    int id = ((blockIdx.x & 4095) << 8) + t;
    int f = id & 255, b = id >> 8;
    ushort* base = D.T + ((size_t)b * nj) * 256 + f;
    float bi = D.bias[f];
    switch (nj) {
        case 25: mix1_body<25>(base, As, bi); break;
        case 5:  mix1_body<5>(base, As, bi); break;
        case 3:  mix1_body<3>(base, As, bi); break;
        default: mix1_body<6>(base, As, bi); break;
    }
}

// ---------------------------------------------------------------------------
// Grouped mix pass 2 (F=512): scatter-form. Region 0: global in-place mix on
// XGL even half (sldr=1024, jm=identity). Regions 1-4: part mix P3 -> XGL
// odd half via joint map. 5 regions x 8192 blocks.
// ---------------------------------------------------------------------------
struct M2Desc {
    const ushort* src; ushort* dst; const float* adj; const float* bias;
    int nj, sldr; int jm[25];
};
struct M2Params { M2Desc d[5]; };

template <int NJ>
__device__ __forceinline__ void mix2_body(const ushort* src, int sldr, ushort* dst,
                                          const int* jms, const float* As, float bi) {
    float v[NJ];
#pragma unroll
    for (int j = 0; j < NJ; j++) v[j] = b2f(src[(size_t)j * sldr]);
#pragma unroll
    for (int i = 0; i < NJ; i++) {
        float o = 0.f;
#pragma unroll
        for (int j = 0; j < NJ; j++) o += As[i * NJ + j] * v[j];
        dst[(size_t)jms[i] * 1024] = f2b(fmaxf(o + bi, 0.f));
    }
}

__global__ __launch_bounds__(256) void mixg2(M2Params P) {
    __shared__ float As[625];
    __shared__ int jms[25];
    int r = blockIdx.x >> 13;
    const M2Desc& D = P.d[r];
    int t = threadIdx.x;
    int nj = D.nj;
    for (int i = t; i < nj * nj; i += 256) As[i] = D.adj[i];
    if (t < nj) jms[t] = D.jm[t];
    __syncthreads();
    int id = ((blockIdx.x & 8191) << 8) + t;
    int f = id & 511, b = id >> 9;
    const ushort* src = D.src + ((size_t)b * nj) * D.sldr + f;
    ushort* dst = D.dst + (size_t)b * 25 * 1024 + f;
    float bi = D.bias[f];
    switch (nj) {
        case 25: mix2_body<25>(src, D.sldr, dst, jms, As, bi); break;
        case 5:  mix2_body<5>(src, D.sldr, dst, jms, As, bi); break;
        case 3:  mix2_body<3>(src, D.sldr, dst, jms, As, bi); break;
        default: mix2_body<6>(src, D.sldr, dst, jms, As, bi); break;
    }
}

// ---------------------------------------------------------------------------
extern "C" void kernel_launch(void* const* d_in, const int* in_sizes, int n_in,
                              void* d_out, int out_size, void* d_ws,
                              size_t ws_size, hipStream_t stream) {
    const float* x    = (const float*)d_in[0];
    const float* adjg = (const float*)d_in[1];
    const float* al0  = (const float*)d_in[2];
    const float* al2  = (const float*)d_in[4];
    const float* al3  = (const float*)d_in[5];
    const float* al4  = (const float*)d_in[6];
    const float* Wg0  = (const float*)d_in[7];
    const float* bg0  = (const float*)d_in[8];
    const float* Wg1  = (const float*)d_in[9];
    const float* bg1  = (const float*)d_in[10];
    const float* Wf0  = (const float*)d_in[31];
    const float* bf0  = (const float*)d_in[32];
    const float* Wf1  = (const float*)d_in[33];
    const float* bf1  = (const float*)d_in[34];

    float* ws = (float*)d_ws;
    float* ADJ = ws;                               // 4096 floats
    ushort* U   = (ushort*)(ws + 4096);
    ushort* Xb  = U;                               // 52.4M (a-pass input)
    ushort* XGL = Xb + (size_t)SZ_FULL;            // 104.9M: [XG | XL] per row
    ushort* T   = XGL + (size_t)MROWS * 1024;      // 26.2M
    ushort* P1  = T + (size_t)MROWS * 256;         // 17.8M (B*17*256)
    ushort* Wb  = P1 + (size_t)BATCH * 17 * 256;   // 2.1M weights
    ushort* P3  = Xb;                              // 35.7M, reuses dead Xb
    ushort* HF  = Xb;                              // fusion hidden, reuses Xb

    ushort* Wg0t = Wb;                             // [256][512]
    ushort* Wg1t = Wb + 131072;                    // [512][256]
    ushort* Wf0t = Wb + 262144;                    // [512][1024]
    ushort* Wf1t = Wb + 786432;                    // [512][512]
    ushort* Wpt  = Wb + 1048576;                   // 4x (Wat 131072 + Wbt 131072)

    struct Part { int n, widx; int idx[6]; };
    const Part parts[4] = {
        {5, 11, {0, 1, 2, 3, 4, 0}},
        {3, 19, {5, 7, 9, 0, 0, 0}},
        {3, 23, {6, 8, 10, 0, 0, 0}},
        {6, 27, {11, 12, 13, 14, 15, 16}},
    };
    const int cumn[4] = {0, 5, 8, 11};

    dim3 blk(256), blk512(512);

    adjnorm_kernel<<<1, blk, 0, stream>>>(adjg, al0, al2, al3, al4, ADJ);
    cvt_bf16<<<SZ_FULL / 4 / 256, blk, 0, stream>>>(x, Xb, SZ_FULL / 4);
    zero_tail<<<16384, blk, 0, stream>>>(XGL);

    // grouped weight transposes (12 regions, 2048 blocks)
    {
        WParams WP{};
        int e = 0, i = 0;
        auto add = [&](const float* W, ushort* Wt, int K, int N) {
            int nx = N >> 5;
            int nxlog = (nx == 8) ? 3 : ((nx == 16) ? 4 : 5);
            e += nx * (K >> 5);
            WP.d[i++] = {W, Wt, K, N, nxlog, e};
        };
        add(Wg0, Wg0t, 512, 256);
        add(Wg1, Wg1t, 256, 512);
        add(Wf0, Wf0t, 1024, 512);
        add(Wf1, Wf1t, 512, 512);
        for (int qv = 0; qv < 4; qv++) {
            add((const float*)d_in[parts[qv].widx], Wpt + qv * 262144, 512, 256);
            add((const float*)d_in[parts[qv].widx + 2], Wpt + qv * 262144 + 131072, 256, 512);
        }
        wtrans_all<<<2048, blk, 0, stream>>>(WP);
    }

    auto setg = [](GDesc& g, const ushort* A, const ushort* Wt, const float* bias,
                   void* C, int K, int lda, int ldc, int nT, int wgEnd, int gn,
                   int flags, const int* map) {
        g.A = A; g.Wt = Wt; g.bias = bias; g.C = C; g.K = K; g.lda = lda;
        g.ldc = ldc; g.nTiles = nT; g.wgEnd = wgEnd; g.gn = gn; g.flags = flags;
        g.pad = 0;
        for (int i = 0; i < 6; i++) g.gmap[i] = map ? map[i] : 0;
    };

    // ---- a-pass: global (400 wg) + 4 local parts (272 wg) = 672 wg ----
    {
        GParams GA{};
        int e = 400;
        setg(GA.g[0], Xb, Wg0t, nullptr, T, 512, 512, 256, 1, e, 0, 0, nullptr);
        for (int qv = 0; qv < 4; qv++) {
            e += parts[qv].n * 16;
            setg(GA.g[1 + qv], Xb, Wpt + qv * 262144, nullptr,
                 P1 + (size_t)BATCH * cumn[qv] * 256,
                 512, 512, 256, 1, e, parts[qv].n, 1, parts[qv].idx);
        }
        gemmg<<<672, blk512, 0, stream>>>(GA);
    }

    // ---- mix pass 1 (F=256): global T + 4 parts P1 ----
    {
        M1Params M1{};
        M1.d[0] = {T, ADJ, bg0, 25};
        for (int qv = 0; qv < 4; qv++)
            M1.d[1 + qv] = {P1 + (size_t)BATCH * cumn[qv] * 256,
                            ADJ + 640 + qv * 64,
                            (const float*)d_in[parts[qv].widx + 1],
                            parts[qv].n};
        mixg1<<<20480, blk, 0, stream>>>(M1);
    }

    // ---- b-pass: global (800 wg) + 4 local parts (544 wg) = 1344 wg ----
    {
        GParams GB{};
        int e = 800;
        setg(GB.g[0], T, Wg1t, nullptr, XGL, 256, 256, 1024, 2, e, 0, 0, nullptr);
        for (int qv = 0; qv < 4; qv++) {
            e += parts[qv].n * 32;
            setg(GB.g[1 + qv], P1 + (size_t)BATCH * cumn[qv] * 256,
                 Wpt + qv * 262144 + 131072, nullptr,
                 P3 + (size_t)BATCH * cumn[qv] * 512,
                 256, 256, 512, 2, e, 0, 0, nullptr);
        }
        gemmg<<<1344, blk512, 0, stream>>>(GB);
    }

    // ---- mix pass 2 (F=512): global XGL in-place + 4 part scatters ----
    {
        M2Params M2{};
        M2.d[0].src = XGL; M2.d[0].dst = XGL; M2.d[0].adj = ADJ;
        M2.d[0].bias = bg1; M2.d[0].nj = 25; M2.d[0].sldr = 1024;
        for (int i = 0; i < 25; i++) M2.d[0].jm[i] = i;
        for (int qv = 0; qv < 4; qv++) {
            M2Desc& D = M2.d[1 + qv];
            D.src = P3 + (size_t)BATCH * cumn[qv] * 512;
            D.dst = XGL + 512;
            D.adj = ADJ + 640 + qv * 64;
            D.bias = (const float*)d_in[parts[qv].widx + 3];
            D.nj = parts[qv].n; D.sldr = 512;
            for (int i = 0; i < 25; i++) D.jm[i] = (i < 6) ? parts[qv].idx[i] : 0;
        }
        mixg2<<<40960, blk, 0, stream>>>(M2);
    }

    // ---- fusion: HF = relu(XGL @ Wf0 + bf0); out = HF @ Wf1 + bf1 (f32) ----
    {
        GParams GF{};
        setg(GF.g[0], XGL, Wf0t, bf0, HF, 1024, 1024, 512, 2, 800, 0, 2 | 4, nullptr);
        gemmg<<<800, blk512, 0, stream>>>(GF);
    }
    {
        GParams GO{};
        setg(GO.g[0], HF, Wf1t, bf1, d_out, 512, 512, 512, 2, 800, 0, 2 | 8, nullptr);
        gemmg<<<800, blk512, 0, stream>>>(GO);
    }

    (void)in_sizes; (void)n_in; (void)out_size; (void)ws_size;
}

// Round 7
// 968.157 us; speedup vs baseline: 1.0533x; 1.0533x over previous
//
#include <hip/hip_runtime.h>

// ---------------------------------------------------------------------------
// GLA_GCN bf16-MFMA pipeline. B=4096, J=25, D_IN=512, D_H=256, D_OUT=512.
// Partition 1 is dead (all its joints overwritten by parts 2/3/4).
// GEMMs are GROUPED: one dispatch for all five "a" GEMMs (672 wg), one for
// all five "b" GEMMs (1344 wg), plus Wf0/Wf1 (800 wg each).
// GEMM inner loop (R2-proven): 256x256 tile, BK=64, 8 waves, 8-phase/iter
// schedule (2 K-tiles per iter, 16 MFMA + one half-tile stage per phase),
// counted vmcnt(4) at P3/P7 (vmcnt(0) only at last-iter P3), 2dbuf x 4
// half-tile LDS (128 KiB), chunk-XOR swizzle (bank-conflict-free
// ds_read_b128), m201 pinning (lgkmcnt(8) hint, sched_barrier+s_barrier+
// lgkmcnt(0)+sched_barrier, setprio around MFMA), XCD block swizzle.
// XG|XL stored interleaved per row (XGL, lda=1024) so fusion GEMM is plain.
// ---------------------------------------------------------------------------

#define BATCH 4096
#define NJOINT 25
#define MROWS (BATCH * NJOINT)          // 102400
#define SZ_FULL (MROWS * 512)           // 52,428,800 bf16 elements

typedef __attribute__((ext_vector_type(8))) short short8;
typedef __attribute__((ext_vector_type(4))) float float4_;

__device__ __forceinline__ float b2f(ushort u) {
    union { float f; uint32_t i; } x; x.i = ((uint32_t)u) << 16; return x.f;
}
__device__ __forceinline__ ushort f2b(float f) {
    union { float f; uint32_t i; } x; x.f = f;
    uint32_t r = x.i + 0x7fff + ((x.i >> 16) & 1);
    return (ushort)(r >> 16);
}
__device__ __forceinline__ void async16(const void* g, void* l) {
    __builtin_amdgcn_global_load_lds(
        (const __attribute__((address_space(1))) void*)g,
        (__attribute__((address_space(3))) void*)l, 16, 0, 0);
}

// ---------------------------------------------------------------------------
// Adjacency normalization (fp32, tiny)
// ---------------------------------------------------------------------------
__device__ void norm_one(const float* A, int n, float* out, float* sAdj, float* sD) {
    int t = threadIdx.x;
    for (int i = t; i < n * n; i += 256) sAdj[i] = A[i];
    __syncthreads();
    if (t < n) {
        float s = 0.f;
        for (int j = 0; j < n; j++) s += sAdj[t * n + j];
        sD[t] = 1.0f / sqrtf(fmaxf(s, 1e-6f));
    }
    __syncthreads();
    for (int i = t; i < n * n; i += 256) {
        int r = i / n, c = i % n;
        out[i] = sD[r] * sAdj[i] * sD[c];
    }
    __syncthreads();
}

__global__ __launch_bounds__(256) void adjnorm_kernel(
    const float* Ag, const float* A0, const float* A2, const float* A3,
    const float* A4, float* ADJ) {
    __shared__ float sAdj[640];
    __shared__ float sD[32];
    norm_one(Ag, 25, ADJ, sAdj, sD);
    norm_one(A0, 5, ADJ + 640 + 0 * 64, sAdj, sD);
    norm_one(A2, 3, ADJ + 640 + 1 * 64, sAdj, sD);
    norm_one(A3, 3, ADJ + 640 + 2 * 64, sAdj, sD);
    norm_one(A4, 6, ADJ + 640 + 3 * 64, sAdj, sD);
}

// ---------------------------------------------------------------------------
// fp32 -> bf16 convert (x), float4 -> ushort4
// ---------------------------------------------------------------------------
__global__ __launch_bounds__(256) void cvt_bf16(const float* __restrict__ in,
                                                ushort* __restrict__ out, int n4) {
    int id = blockIdx.x * 256 + threadIdx.x;
    if (id < n4) {
        float4 v = ((const float4*)in)[id];
        ushort4 o;
        o.x = f2b(v.x); o.y = f2b(v.y); o.z = f2b(v.z); o.w = f2b(v.w);
        ((ushort4*)out)[id] = o;
    }
}

// ---------------------------------------------------------------------------
// Grouped weight transpose: W fp32 [K][N] -> Wt bf16 [N][K], 12 regions.
// ---------------------------------------------------------------------------
struct WDesc { const float* W; ushort* Wt; int K, N, nxlog, end; };
struct WParams { WDesc d[12]; };

__global__ __launch_bounds__(256) void wtrans_all(WParams P) {
    __shared__ float tile[32][33];
    int bid = blockIdx.x;
    int i = 0, start = 0;
    while (bid >= P.d[i].end) { start = P.d[i].end; i++; }
    const WDesc& D = P.d[i];
    int local = bid - start;
    int bx = local & ((1 << D.nxlog) - 1);
    int by = local >> D.nxlog;
    int K = D.K, N = D.N;
    int t = threadIdx.x, tx = t & 31, ty = t >> 5;
    int k0 = by * 32, n0 = bx * 32;
    for (int r = ty; r < 32; r += 8)
        tile[r][tx] = D.W[(size_t)(k0 + r) * N + n0 + tx];
    __syncthreads();
    for (int r = ty; r < 32; r += 8)
        D.Wt[(size_t)(n0 + r) * K + k0 + tx] = f2b(tile[tx][r]);
}

// ---------------------------------------------------------------------------
// Zero XL joints 17..24 in XGL interleaved layout (row stride 1024, XL at +512)
// ---------------------------------------------------------------------------
__global__ __launch_bounds__(256) void zero_tail(ushort* __restrict__ XGL) {
    int id = blockIdx.x * 256 + threadIdx.x;
    int f4 = id & 127;
    int rj = (id >> 7) & 7;
    int b = id >> 10;
    ushort4 z; z.x = 0; z.y = 0; z.z = 0; z.w = 0;
    ((ushort4*)(XGL + ((size_t)(b * 25 + 17 + rj) * 1024 + 512)))[f4] = z;
}

// ---------------------------------------------------------------------------
// Grouped bf16 MFMA GEMM, 8-phase schedule (R2 discipline).
//   Per group: C[M,N] = act(A @ Wt^T [+ bias]); A row-major (lda),
//   Wt [N][K], C (ldc). flags: 1=GATHER, 2=BIAS, 4=RELU, 8=OUTF32.
//   256x256 tile, BK=64, 8 waves (2Mx4N), per-wave 128x64 via 8x4x2 of
//   mfma_f32_16x16x32_bf16. LDS: 2 dbuf x {A0,A1,B0,B1} 16 KiB half-tiles.
//   One iteration = 2 K-tiles = 8 phases; each phase computes one fi-pair
//   (16 MFMA) and stages one half-tile (2 async16/thread).
//   Stage stream (iter j): P0/P1: kt(2j+1).A0/A1 -> dbuf1; P2/P3:
//   kt(2j+2).B0/B1 -> dbuf0; P4/P5: kt(2j+2).A0/A1 -> dbuf0; P6/P7:
//   kt(2j+3).B0/B1 -> dbuf1. vmcnt(4) at P3 (covers dbuf1 for P4..P7)
//   and P7 (covers dbuf0 for next P0..P3); last-iter P3 uses vmcnt(0).
//   Every wait is barrier-separated from the first read of the data it
//   covers -> cross-wave safety transitive through phase barriers.
//   Swizzle: rows of 8 x 16B chunks; linear LDS dest, source chunk =
//   lanechunk ^ (row&7), read chunk = (q or q^4) ^ (row&7) => conflict-free.
// ---------------------------------------------------------------------------
struct GDesc {
    const ushort* A; const ushort* Wt; const float* bias; void* C;
    int K, lda, ldc, nTiles, wgEnd, gn, flags, pad;
    int gmap[6];
};
struct GParams { GDesc g[5]; };

__global__ __launch_bounds__(512, 2) void gemmg(GParams P) {
    __shared__ ushort lds[65536];   // 128 KiB: [2 dbuf][4 slots][8192]
    int t = threadIdx.x;
    int l = t & 63, w = t >> 6;

    // bijective XCD swizzle (all grids are multiples of 8)
    int nwg = (int)gridDim.x;
    int cpx = nwg >> 3;
    int wg = ((int)blockIdx.x & 7) * cpx + ((int)blockIdx.x >> 3);

    int gi = 0, wg0 = 0;
    while (wg >= P.g[gi].wgEnd) { wg0 = P.g[gi].wgEnd; gi++; }
    const GDesc& G = P.g[gi];
    int lw = wg - wg0;
    int tm, tn;
    if (G.nTiles == 2) { tm = lw >> 1; tn = lw & 1; }
    else               { tm = lw;      tn = 0; }
    int bm = tm << 8, bn = tn << 8;
    const int K = G.K, lda = G.lda, ldc = G.ldc;
    const bool GATHER = (G.flags & 1) != 0;
    const bool BIAS   = (G.flags & 2) != 0;
    const bool RELU   = (G.flags & 4) != 0;
    const bool OUTF32 = (G.flags & 8) != 0;

    // staging: lane l covers row (l>>3), linear chunk (l&7); source chunk
    // pre-swizzled by ^(row&7) = ^(l>>3)
    int srow = (w << 4) + (l >> 3);
    int sch = ((l & 7) ^ (l >> 3)) << 3;
    const ushort* pA[2][2];
    const ushort* pB[2][2];
#pragma unroll
    for (int h = 0; h < 2; h++)
#pragma unroll
        for (int i = 0; i < 2; i++) {
            int r = bm + h * 128 + srow + i * 8;
            if (GATHER) { int b = r / G.gn; r = b * 25 + G.gmap[r - b * G.gn]; }
            pA[h][i] = G.A + (size_t)r * lda + sch;
            int c = bn + h * 128 + srow + i * 8;
            pB[h][i] = G.Wt + (size_t)c * K + sch;
        }
    int stga = w << 10;

    // fragment read offsets
    int wm = w >> 2, wn = w & 3;
    int lr = l & 15, q = l >> 4;
    int cx = lr & 7;
    int ca0 = (q ^ cx) << 3;
    int ca1 = ca0 ^ 32;
    int ra = (wm << 13) + (lr << 6);
    int rb = 16384 + ((wn >> 1) << 13) + ((wn & 1) << 12) + (lr << 6);

    float4_ acc[8][4];
#pragma unroll
    for (int fi = 0; fi < 8; fi++)
#pragma unroll
        for (int fj = 0; fj < 4; fj++) acc[fi][fj] = (float4_)0.f;
    short8 bfr[4][2];

#define STG_A(DB, H, KT) do {                                              \
        async16(pA[H][0] + (KT) * 64, &lds[(DB) + (H) * 8192 + stga]);     \
        async16(pA[H][1] + (KT) * 64, &lds[(DB) + (H) * 8192 + stga + 512]); \
    } while (0)
#define STG_B(DB, H, KT) do {                                              \
        async16(pB[H][0] + (KT) * 64, &lds[(DB) + 16384 + (H) * 8192 + stga]); \
        async16(pB[H][1] + (KT) * 64, &lds[(DB) + 16384 + (H) * 8192 + stga + 512]); \
    } while (0)

#define DO_PHASE(DB, FI0, RDB, WAITST, STMT) do {                          \
        short8 af00, af01, af10, af11;                                     \
        if (RDB) {                                                         \
            _Pragma("unroll")                                              \
            for (int fj = 0; fj < 4; fj++) {                               \
                bfr[fj][0] = *(const short8*)&lds[(DB) + rb + fj * 1024 + ca0]; \
                bfr[fj][1] = *(const short8*)&lds[(DB) + rb + fj * 1024 + ca1]; \
            }                                                              \
        }                                                                  \
        af00 = *(const short8*)&lds[(DB) + ra + (FI0) * 1024 + ca0];       \
        af01 = *(const short8*)&lds[(DB) + ra + (FI0) * 1024 + ca1];       \
        af10 = *(const short8*)&lds[(DB) + ra + ((FI0) + 1) * 1024 + ca0]; \
        af11 = *(const short8*)&lds[(DB) + ra + ((FI0) + 1) * 1024 + ca1]; \
        STMT                                                               \
        WAITST                                                             \
        if (RDB) asm volatile("s_waitcnt lgkmcnt(8)");                     \
        __builtin_amdgcn_sched_barrier(0);                                 \
        __builtin_amdgcn_s_barrier();                                      \
        asm volatile("s_waitcnt lgkmcnt(0)" ::: "memory");                 \
        __builtin_amdgcn_sched_barrier(0);                                 \
        __builtin_amdgcn_s_setprio(1);                                     \
        _Pragma("unroll")                                                  \
        for (int fj = 0; fj < 4; fj++) {                                   \
            acc[FI0][fj] = __builtin_amdgcn_mfma_f32_16x16x32_bf16(        \
                af00, bfr[fj][0], acc[FI0][fj], 0, 0, 0);                  \
            acc[FI0][fj] = __builtin_amdgcn_mfma_f32_16x16x32_bf16(        \
                af01, bfr[fj][1], acc[FI0][fj], 0, 0, 0);                  \
            acc[(FI0) + 1][fj] = __builtin_amdgcn_mfma_f32_16x16x32_bf16(  \
                af10, bfr[fj][0], acc[(FI0) + 1][fj], 0, 0, 0);            \
            acc[(FI0) + 1][fj] = __builtin_amdgcn_mfma_f32_16x16x32_bf16(  \
                af11, bfr[fj][1], acc[(FI0) + 1][fj], 0, 0, 0);            \
        }                                                                  \
        __builtin_amdgcn_s_setprio(0);                                     \
        __builtin_amdgcn_sched_barrier(0);                                 \
        __builtin_amdgcn_s_barrier();                                      \
    } while (0)

    int NT = K >> 6;              // K-tiles of 64 (NT even, >= 4 here)
    int NITER = NT >> 1;

    // prologue: kt0 complete + kt1.B; wait for kt0, barrier.
    STG_A(0, 0, 0); STG_A(0, 1, 0);
    STG_B(0, 0, 0); STG_B(0, 1, 0);
    STG_B(32768, 0, 1); STG_B(32768, 1, 1);
    asm volatile("s_waitcnt vmcnt(4)" ::: "memory");
    __builtin_amdgcn_sched_barrier(0);
    __builtin_amdgcn_s_barrier();

    for (int j = 0; j < NITER; ++j) {
        int k1 = 2 * j + 1, k2 = 2 * j + 2, k3 = 2 * j + 3;
        bool nl = (j + 1 < NITER);
        DO_PHASE(0, 0, true, , STG_A(32768, 0, k1););
        DO_PHASE(0, 2, false, , STG_A(32768, 1, k1););
        DO_PHASE(0, 4, false, , if (nl) STG_B(0, 0, k2););
        DO_PHASE(0, 6, false,
                 if (nl) { asm volatile("s_waitcnt vmcnt(4)" ::: "memory"); }
                 else    { asm volatile("s_waitcnt vmcnt(0)" ::: "memory"); },
                 if (nl) STG_B(0, 1, k2););
        DO_PHASE(32768, 0, true, , if (nl) STG_A(0, 0, k2););
        DO_PHASE(32768, 2, false, , if (nl) STG_A(0, 1, k2););
        DO_PHASE(32768, 4, false, , if (nl) STG_B(32768, 0, k3););
        DO_PHASE(32768, 6, false,
                 if (nl) { asm volatile("s_waitcnt vmcnt(4)" ::: "memory"); },
                 if (nl) STG_B(32768, 1, k3););
    }
#undef DO_PHASE
#undef STG_A
#undef STG_B

    // epilogue: C/D layout col=lane&15, row=(lane>>4)*4+reg
    int cl = lr;
    float bv[4];
#pragma unroll
    for (int fj = 0; fj < 4; fj++)
        bv[fj] = BIAS ? G.bias[bn + (wn << 6) + (fj << 4) + cl] : 0.f;
#pragma unroll
    for (int fi = 0; fi < 8; fi++) {
        int row0 = bm + (wm << 7) + (fi << 4) + (q << 2);
#pragma unroll
        for (int r = 0; r < 4; r++) {
            size_t rowoff = (size_t)(row0 + r) * ldc;
#pragma unroll
            for (int fj = 0; fj < 4; fj++) {
                int col = bn + (wn << 6) + (fj << 4) + cl;
                float v = acc[fi][fj][r] + bv[fj];
                if (RELU) v = fmaxf(v, 0.f);
                if (OUTF32)
                    ((float*)G.C)[rowoff + col] = v;
                else
                    ((ushort*)G.C)[rowoff + col] = f2b(v);
            }
        }
    }
}

// ---------------------------------------------------------------------------
// Grouped mix pass 1 (F=256): T[b,i,f] = relu(sum_j adj[i,j]*T[b,j,f]+bias[f])
// 5 regions x 4096 blocks.
// ---------------------------------------------------------------------------
struct M1Desc { ushort* T; const float* adj; const float* bias; int nj; };
struct M1Params { M1Desc d[5]; };

template <int NJ>
__device__ __forceinline__ void mix1_body(ushort* base, const float* As, float bi) {
    float v[NJ];
#pragma unroll
    for (int j = 0; j < NJ; j++) v[j] = b2f(base[(size_t)j * 256]);
#pragma unroll
    for (int i = 0; i < NJ; i++) {
        float o = 0.f;
#pragma unroll
        for (int j = 0; j < NJ; j++) o += As[i * NJ + j] * v[j];
        base[(size_t)i * 256] = f2b(fmaxf(o + bi, 0.f));
    }
}

__global__ __launch_bounds__(256) void mixg1(M1Params P) {
    __shared__ float As[625];
    int r = blockIdx.x >> 12;
    const M1Desc& D = P.d[r];
    int t = threadIdx.x;
    int nj = D.nj;
    for (int i = t; i < nj * nj; i += 256) As[i] = D.adj[i];
    __syncthreads();
    int id = ((blockIdx.x & 4095) << 8) + t;
    int f = id & 255, b = id >> 8;
    ushort* base = D.T + ((size_t)b * nj) * 256 + f;
    float bi = D.bias[f];
    switch (nj) {
        case 25: mix1_body<25>(base, As, bi); break;
        case 5:  mix1_body<5>(base, As, bi); break;
        case 3:  mix1_body<3>(base, As, bi); break;
        default: mix1_body<6>(base, As, bi); break;
    }
}

// ---------------------------------------------------------------------------
// Grouped mix pass 2 (F=512): scatter-form. Region 0: global in-place mix on
// XGL even half (sldr=1024, jm=identity). Regions 1-4: part mix P3 -> XGL
// odd half via joint map. 5 regions x 8192 blocks.
// ---------------------------------------------------------------------------
struct M2Desc {
    const ushort* src; ushort* dst; const float* adj; const float* bias;
    int nj, sldr; int jm[25];
};
struct M2Params { M2Desc d[5]; };

template <int NJ>
__device__ __forceinline__ void mix2_body(const ushort* src, int sldr, ushort* dst,
                                          const int* jms, const float* As, float bi) {
    float v[NJ];
#pragma unroll
    for (int j = 0; j < NJ; j++) v[j] = b2f(src[(size_t)j * sldr]);
#pragma unroll
    for (int i = 0; i < NJ; i++) {
        float o = 0.f;
#pragma unroll
        for (int j = 0; j < NJ; j++) o += As[i * NJ + j] * v[j];
        dst[(size_t)jms[i] * 1024] = f2b(fmaxf(o + bi, 0.f));
    }
}

__global__ __launch_bounds__(256) void mixg2(M2Params P) {
    __shared__ float As[625];
    __shared__ int jms[25];
    int r = blockIdx.x >> 13;
    const M2Desc& D = P.d[r];
    int t = threadIdx.x;
    int nj = D.nj;
    for (int i = t; i < nj * nj; i += 256) As[i] = D.adj[i];
    if (t < nj) jms[t] = D.jm[t];
    __syncthreads();
    int id = ((blockIdx.x & 8191) << 8) + t;
    int f = id & 511, b = id >> 9;
    const ushort* src = D.src + ((size_t)b * nj) * D.sldr + f;
    ushort* dst = D.dst + (size_t)b * 25 * 1024 + f;
    float bi = D.bias[f];
    switch (nj) {
        case 25: mix2_body<25>(src, D.sldr, dst, jms, As, bi); break;
        case 5:  mix2_body<5>(src, D.sldr, dst, jms, As, bi); break;
        case 3:  mix2_body<3>(src, D.sldr, dst, jms, As, bi); break;
        default: mix2_body<6>(src, D.sldr, dst, jms, As, bi); break;
    }
}

// ---------------------------------------------------------------------------
extern "C" void kernel_launch(void* const* d_in, const int* in_sizes, int n_in,
                              void* d_out, int out_size, void* d_ws,
                              size_t ws_size, hipStream_t stream) {
    const float* x    = (const float*)d_in[0];
    const float* adjg = (const float*)d_in[1];
    const float* al0  = (const float*)d_in[2];
    const float* al2  = (const float*)d_in[4];
    const float* al3  = (const float*)d_in[5];
    const float* al4  = (const float*)d_in[6];
    const float* Wg0  = (const float*)d_in[7];
    const float* bg0  = (const float*)d_in[8];
    const float* Wg1  = (const float*)d_in[9];
    const float* bg1  = (const float*)d_in[10];
    const float* Wf0  = (const float*)d_in[31];
    const float* bf0  = (const float*)d_in[32];
    const float* Wf1  = (const float*)d_in[33];
    const float* bf1  = (const float*)d_in[34];

    float* ws = (float*)d_ws;
    float* ADJ = ws;                               // 4096 floats
    ushort* U   = (ushort*)(ws + 4096);
    ushort* Xb  = U;                               // 52.4M (a-pass input)
    ushort* XGL = Xb + (size_t)SZ_FULL;            // 104.9M: [XG | XL] per row
    ushort* T   = XGL + (size_t)MROWS * 1024;      // 26.2M
    ushort* P1  = T + (size_t)MROWS * 256;         // 17.8M (B*17*256)
    ushort* Wb  = P1 + (size_t)BATCH * 17 * 256;   // 2.1M weights
    ushort* P3  = Xb;                              // 35.7M, reuses dead Xb
    ushort* HF  = Xb;                              // fusion hidden, reuses Xb

    ushort* Wg0t = Wb;                             // [256][512]
    ushort* Wg1t = Wb + 131072;                    // [512][256]
    ushort* Wf0t = Wb + 262144;                    // [512][1024]
    ushort* Wf1t = Wb + 786432;                    // [512][512]
    ushort* Wpt  = Wb + 1048576;                   // 4x (Wat 131072 + Wbt 131072)

    struct Part { int n, widx; int idx[6]; };
    const Part parts[4] = {
        {5, 11, {0, 1, 2, 3, 4, 0}},
        {3, 19, {5, 7, 9, 0, 0, 0}},
        {3, 23, {6, 8, 10, 0, 0, 0}},
        {6, 27, {11, 12, 13, 14, 15, 16}},
    };
    const int cumn[4] = {0, 5, 8, 11};

    dim3 blk(256), blk512(512);

    adjnorm_kernel<<<1, blk, 0, stream>>>(adjg, al0, al2, al3, al4, ADJ);
    cvt_bf16<<<SZ_FULL / 4 / 256, blk, 0, stream>>>(x, Xb, SZ_FULL / 4);
    zero_tail<<<16384, blk, 0, stream>>>(XGL);

    // grouped weight transposes (12 regions, 2048 blocks)
    {
        WParams WP{};
        int e = 0, i = 0;
        auto add = [&](const float* W, ushort* Wt, int K, int N) {
            int nx = N >> 5;
            int nxlog = (nx == 8) ? 3 : ((nx == 16) ? 4 : 5);
            e += nx * (K >> 5);
            WP.d[i++] = {W, Wt, K, N, nxlog, e};
        };
        add(Wg0, Wg0t, 512, 256);
        add(Wg1, Wg1t, 256, 512);
        add(Wf0, Wf0t, 1024, 512);
        add(Wf1, Wf1t, 512, 512);
        for (int qv = 0; qv < 4; qv++) {
            add((const float*)d_in[parts[qv].widx], Wpt + qv * 262144, 512, 256);
            add((const float*)d_in[parts[qv].widx + 2], Wpt + qv * 262144 + 131072, 256, 512);
        }
        wtrans_all<<<2048, blk, 0, stream>>>(WP);
    }

    auto setg = [](GDesc& g, const ushort* A, const ushort* Wt, const float* bias,
                   void* C, int K, int lda, int ldc, int nT, int wgEnd, int gn,
                   int flags, const int* map) {
        g.A = A; g.Wt = Wt; g.bias = bias; g.C = C; g.K = K; g.lda = lda;
        g.ldc = ldc; g.nTiles = nT; g.wgEnd = wgEnd; g.gn = gn; g.flags = flags;
        g.pad = 0;
        for (int i = 0; i < 6; i++) g.gmap[i] = map ? map[i] : 0;
    };

    // ---- a-pass: global (400 wg) + 4 local parts (272 wg) = 672 wg ----
    {
        GParams GA{};
        int e = 400;
        setg(GA.g[0], Xb, Wg0t, nullptr, T, 512, 512, 256, 1, e, 0, 0, nullptr);
        for (int qv = 0; qv < 4; qv++) {
            e += parts[qv].n * 16;
            setg(GA.g[1 + qv], Xb, Wpt + qv * 262144, nullptr,
                 P1 + (size_t)BATCH * cumn[qv] * 256,
                 512, 512, 256, 1, e, parts[qv].n, 1, parts[qv].idx);
        }
        gemmg<<<672, blk512, 0, stream>>>(GA);
    }

    // ---- mix pass 1 (F=256): global T + 4 parts P1 ----
    {
        M1Params M1{};
        M1.d[0] = {T, ADJ, bg0, 25};
        for (int qv = 0; qv < 4; qv++)
            M1.d[1 + qv] = {P1 + (size_t)BATCH * cumn[qv] * 256,
                            ADJ + 640 + qv * 64,
                            (const float*)d_in[parts[qv].widx + 1],
                            parts[qv].n};
        mixg1<<<20480, blk, 0, stream>>>(M1);
    }

    // ---- b-pass: global (800 wg) + 4 local parts (544 wg) = 1344 wg ----
    {
        GParams GB{};
        int e = 800;
        setg(GB.g[0], T, Wg1t, nullptr, XGL, 256, 256, 1024, 2, e, 0, 0, nullptr);
        for (int qv = 0; qv < 4; qv++) {
            e += parts[qv].n * 32;
            setg(GB.g[1 + qv], P1 + (size_t)BATCH * cumn[qv] * 256,
                 Wpt + qv * 262144 + 131072, nullptr,
                 P3 + (size_t)BATCH * cumn[qv] * 512,
                 256, 256, 512, 2, e, 0, 0, nullptr);
        }
        gemmg<<<1344, blk512, 0, stream>>>(GB);
    }

    // ---- mix pass 2 (F=512): global XGL in-place + 4 part scatters ----
    {
        M2Params M2{};
        M2.d[0].src = XGL; M2.d[0].dst = XGL; M2.d[0].adj = ADJ;
        M2.d[0].bias = bg1; M2.d[0].nj = 25; M2.d[0].sldr = 1024;
        for (int i = 0; i < 25; i++) M2.d[0].jm[i] = i;
        for (int qv = 0; qv < 4; qv++) {
            M2Desc& D = M2.d[1 + qv];
            D.src = P3 + (size_t)BATCH * cumn[qv] * 512;
            D.dst = XGL + 512;
            D.adj = ADJ + 640 + qv * 64;
            D.bias = (const float*)d_in[parts[qv].widx + 3];
            D.nj = parts[qv].n; D.sldr = 512;
            for (int i = 0; i < 25; i++) D.jm[i] = (i < 6) ? parts[qv].idx[i] : 0;
        }
        mixg2<<<40960, blk, 0, stream>>>(M2);
    }

    // ---- fusion: HF = relu(XGL @ Wf0 + bf0); out = HF @ Wf1 + bf1 (f32) ----
    {
        GParams GF{};
        setg(GF.g[0], XGL, Wf0t, bf0, HF, 1024, 1024, 512, 2, 800, 0, 2 | 4, nullptr);
        gemmg<<<800, blk512, 0, stream>>>(GF);
    }
    {
        GParams GO{};
        setg(GO.g[0], HF, Wf1t, bf1, d_out, 512, 512, 512, 2, 800, 0, 2 | 8, nullptr);
        gemmg<<<800, blk512, 0, stream>>>(GO);
    }

    (void)in_sizes; (void)n_in; (void)out_size; (void)ws_size;
}

// Round 8
// 956.604 us; speedup vs baseline: 1.0660x; 1.0121x over previous
//
#include <hip/hip_runtime.h>

// ---------------------------------------------------------------------------
// GLA_GCN bf16-MFMA pipeline. B=4096, J=25, D_IN=512, D_H=256, D_OUT=512.
// Partition 1 is dead (all its joints overwritten by parts 2/3/4).
// GEMMs are GROUPED: one dispatch for all five "a" GEMMs (672 wg), one for
// all five "b" GEMMs (1344 wg), plus Wf0/Wf1 (800 wg each).
// GEMM inner loop: 256x256 tile, BK=64, 8 waves, 8-phase/iter schedule,
// ONE barrier per phase (single-barrier invariant: every stage overwrites a
// slot last read >=2 phases back; every buffer's covering vmcnt-wait is
// barrier-separated from its first read), counted vmcnt(4) at P3/P7
// (vmcnt(0) only at last-iter P3), 2dbuf x 4 half-tile LDS (128 KiB),
// chunk-XOR swizzle (bank-conflict-free ds_read_b128), compiler-managed
// lgkm waits (no hard lgkmcnt(0)), setprio around MFMA, sched_barrier(0)
// fences on both sides of each s_barrier, XCD block swizzle.
// XG|XL stored interleaved per row (XGL, lda=1024) so fusion GEMM is plain.
// ---------------------------------------------------------------------------

#define BATCH 4096
#define NJOINT 25
#define MROWS (BATCH * NJOINT)          // 102400
#define SZ_FULL (MROWS * 512)           // 52,428,800 bf16 elements

typedef __attribute__((ext_vector_type(8))) short short8;
typedef __attribute__((ext_vector_type(4))) float float4_;

__device__ __forceinline__ float b2f(ushort u) {
    union { float f; uint32_t i; } x; x.i = ((uint32_t)u) << 16; return x.f;
}
__device__ __forceinline__ ushort f2b(float f) {
    union { float f; uint32_t i; } x; x.f = f;
    uint32_t r = x.i + 0x7fff + ((x.i >> 16) & 1);
    return (ushort)(r >> 16);
}
__device__ __forceinline__ void async16(const void* g, void* l) {
    __builtin_amdgcn_global_load_lds(
        (const __attribute__((address_space(1))) void*)g,
        (__attribute__((address_space(3))) void*)l, 16, 0, 0);
}

// ---------------------------------------------------------------------------
// Adjacency normalization (fp32, tiny)
// ---------------------------------------------------------------------------
__device__ void norm_one(const float* A, int n, float* out, float* sAdj, float* sD) {
    int t = threadIdx.x;
    for (int i = t; i < n * n; i += 256) sAdj[i] = A[i];
    __syncthreads();
    if (t < n) {
        float s = 0.f;
        for (int j = 0; j < n; j++) s += sAdj[t * n + j];
        sD[t] = 1.0f / sqrtf(fmaxf(s, 1e-6f));
    }
    __syncthreads();
    for (int i = t; i < n * n; i += 256) {
        int r = i / n, c = i % n;
        out[i] = sD[r] * sAdj[i] * sD[c];
    }
    __syncthreads();
}

__global__ __launch_bounds__(256) void adjnorm_kernel(
    const float* Ag, const float* A0, const float* A2, const float* A3,
    const float* A4, float* ADJ) {
    __shared__ float sAdj[640];
    __shared__ float sD[32];
    norm_one(Ag, 25, ADJ, sAdj, sD);
    norm_one(A0, 5, ADJ + 640 + 0 * 64, sAdj, sD);
    norm_one(A2, 3, ADJ + 640 + 1 * 64, sAdj, sD);
    norm_one(A3, 3, ADJ + 640 + 2 * 64, sAdj, sD);
    norm_one(A4, 6, ADJ + 640 + 3 * 64, sAdj, sD);
}

// ---------------------------------------------------------------------------
// fp32 -> bf16 convert (x), float4 -> ushort4
// ---------------------------------------------------------------------------
__global__ __launch_bounds__(256) void cvt_bf16(const float* __restrict__ in,
                                                ushort* __restrict__ out, int n4) {
    int id = blockIdx.x * 256 + threadIdx.x;
    if (id < n4) {
        float4 v = ((const float4*)in)[id];
        ushort4 o;
        o.x = f2b(v.x); o.y = f2b(v.y); o.z = f2b(v.z); o.w = f2b(v.w);
        ((ushort4*)out)[id] = o;
    }
}

// ---------------------------------------------------------------------------
// Grouped weight transpose: W fp32 [K][N] -> Wt bf16 [N][K], 12 regions.
// ---------------------------------------------------------------------------
struct WDesc { const float* W; ushort* Wt; int K, N, nxlog, end; };
struct WParams { WDesc d[12]; };

__global__ __launch_bounds__(256) void wtrans_all(WParams P) {
    __shared__ float tile[32][33];
    int bid = blockIdx.x;
    int i = 0, start = 0;
    while (bid >= P.d[i].end) { start = P.d[i].end; i++; }
    const WDesc& D = P.d[i];
    int local = bid - start;
    int bx = local & ((1 << D.nxlog) - 1);
    int by = local >> D.nxlog;
    int K = D.K, N = D.N;
    int t = threadIdx.x, tx = t & 31, ty = t >> 5;
    int k0 = by * 32, n0 = bx * 32;
    for (int r = ty; r < 32; r += 8)
        tile[r][tx] = D.W[(size_t)(k0 + r) * N + n0 + tx];
    __syncthreads();
    for (int r = ty; r < 32; r += 8)
        D.Wt[(size_t)(n0 + r) * K + k0 + tx] = f2b(tile[tx][r]);
}

// ---------------------------------------------------------------------------
// Zero XL joints 17..24 in XGL interleaved layout (row stride 1024, XL at +512)
// ---------------------------------------------------------------------------
__global__ __launch_bounds__(256) void zero_tail(ushort* __restrict__ XGL) {
    int id = blockIdx.x * 256 + threadIdx.x;
    int f4 = id & 127;
    int rj = (id >> 7) & 7;
    int b = id >> 10;
    ushort4 z; z.x = 0; z.y = 0; z.z = 0; z.w = 0;
    ((ushort4*)(XGL + ((size_t)(b * 25 + 17 + rj) * 1024 + 512)))[f4] = z;
}

// ---------------------------------------------------------------------------
// Grouped bf16 MFMA GEMM, 8-phase schedule, ONE barrier per phase.
//   Per group: C[M,N] = act(A @ Wt^T [+ bias]); A row-major (lda),
//   Wt [N][K], C (ldc). flags: 1=GATHER, 2=BIAS, 4=RELU, 8=OUTF32.
//   256x256 tile, BK=64, 8 waves (2Mx4N), per-wave 128x64 via 8x4x2 of
//   mfma_f32_16x16x32_bf16. LDS: 2 dbuf x {A0,A1,B0,B1} 16 KiB half-tiles.
//   One iteration = 2 K-tiles = 8 phases; each phase: {ds_read fragments,
//   stage-issue one half-tile, [vmcnt], setprio(1) 16 MFMA setprio(0),
//   sched_barrier / s_barrier / sched_barrier}.
//   Stage stream (iter j): P0/P1: kt(2j+1).A0/A1 -> dbuf1; P2/P3:
//   kt(2j+2).B0/B1 -> dbuf0; P4/P5: kt(2j+2).A0/A1 -> dbuf0; P6/P7:
//   kt(2j+3).B0/B1 -> dbuf1. vmcnt(4) at P3 (A(k1) done -> dbuf1 valid for
//   P4) and P7 (A(k2) done, B(k2) older -> dbuf0 valid for next P0);
//   last-iter P3 uses vmcnt(0).
//   Single-barrier race analysis: (1) stage(p) overwrites a slot whose last
//   reader phase is <= p-2, so >=2 end-of-phase barriers separate them;
//   (2) reads(p) of slot S follow S's covering vmcnt-wait (phase p-1, before
//   barrier(p-1)) -> barrier-transitive across waves. sched_barrier(0) on
//   both sides of s_barrier stops the compiler moving reads/stages across.
//   Swizzle: rows of 8 x 16B chunks; linear LDS dest, source chunk =
//   lanechunk ^ (row&7), read chunk = (q or q^4) ^ (row&7) => conflict-free.
// ---------------------------------------------------------------------------
struct GDesc {
    const ushort* A; const ushort* Wt; const float* bias; void* C;
    int K, lda, ldc, nTiles, wgEnd, gn, flags, pad;
    int gmap[6];
};
struct GParams { GDesc g[5]; };

__global__ __launch_bounds__(512, 2) void gemmg(GParams P) {
    __shared__ ushort lds[65536];   // 128 KiB: [2 dbuf][4 slots][8192]
    int t = threadIdx.x;
    int l = t & 63, w = t >> 6;

    // bijective XCD swizzle (all grids are multiples of 8)
    int nwg = (int)gridDim.x;
    int cpx = nwg >> 3;
    int wg = ((int)blockIdx.x & 7) * cpx + ((int)blockIdx.x >> 3);

    int gi = 0, wg0 = 0;
    while (wg >= P.g[gi].wgEnd) { wg0 = P.g[gi].wgEnd; gi++; }
    const GDesc& G = P.g[gi];
    int lw = wg - wg0;
    int tm, tn;
    if (G.nTiles == 2) { tm = lw >> 1; tn = lw & 1; }
    else               { tm = lw;      tn = 0; }
    int bm = tm << 8, bn = tn << 8;
    const int K = G.K, lda = G.lda, ldc = G.ldc;
    const bool GATHER = (G.flags & 1) != 0;
    const bool BIAS   = (G.flags & 2) != 0;
    const bool RELU   = (G.flags & 4) != 0;
    const bool OUTF32 = (G.flags & 8) != 0;

    // staging: lane l covers row (l>>3), linear chunk (l&7); source chunk
    // pre-swizzled by ^(row&7) = ^(l>>3)
    int srow = (w << 4) + (l >> 3);
    int sch = ((l & 7) ^ (l >> 3)) << 3;
    const ushort* pA[2][2];
    const ushort* pB[2][2];
#pragma unroll
    for (int h = 0; h < 2; h++)
#pragma unroll
        for (int i = 0; i < 2; i++) {
            int r = bm + h * 128 + srow + i * 8;
            if (GATHER) { int b = r / G.gn; r = b * 25 + G.gmap[r - b * G.gn]; }
            pA[h][i] = G.A + (size_t)r * lda + sch;
            int c = bn + h * 128 + srow + i * 8;
            pB[h][i] = G.Wt + (size_t)c * K + sch;
        }
    int stga = w << 10;

    // fragment read offsets
    int wm = w >> 2, wn = w & 3;
    int lr = l & 15, q = l >> 4;
    int cx = lr & 7;
    int ca0 = (q ^ cx) << 3;
    int ca1 = ca0 ^ 32;
    int ra = (wm << 13) + (lr << 6);
    int rb = 16384 + ((wn >> 1) << 13) + ((wn & 1) << 12) + (lr << 6);

    float4_ acc[8][4];
#pragma unroll
    for (int fi = 0; fi < 8; fi++)
#pragma unroll
        for (int fj = 0; fj < 4; fj++) acc[fi][fj] = (float4_)0.f;
    short8 bfr[4][2];

#define STG_A(DB, H, KT) do {                                              \
        async16(pA[H][0] + (KT) * 64, &lds[(DB) + (H) * 8192 + stga]);     \
        async16(pA[H][1] + (KT) * 64, &lds[(DB) + (H) * 8192 + stga + 512]); \
    } while (0)
#define STG_B(DB, H, KT) do {                                              \
        async16(pB[H][0] + (KT) * 64, &lds[(DB) + 16384 + (H) * 8192 + stga]); \
        async16(pB[H][1] + (KT) * 64, &lds[(DB) + 16384 + (H) * 8192 + stga + 512]); \
    } while (0)

#define DO_PHASE(DB, FI0, RDB, WAITST, STMT) do {                          \
        short8 af00, af01, af10, af11;                                     \
        if (RDB) {                                                         \
            _Pragma("unroll")                                              \
            for (int fj = 0; fj < 4; fj++) {                               \
                bfr[fj][0] = *(const short8*)&lds[(DB) + rb + fj * 1024 + ca0]; \
                bfr[fj][1] = *(const short8*)&lds[(DB) + rb + fj * 1024 + ca1]; \
            }                                                              \
        }                                                                  \
        af00 = *(const short8*)&lds[(DB) + ra + (FI0) * 1024 + ca0];       \
        af01 = *(const short8*)&lds[(DB) + ra + (FI0) * 1024 + ca1];       \
        af10 = *(const short8*)&lds[(DB) + ra + ((FI0) + 1) * 1024 + ca0]; \
        af11 = *(const short8*)&lds[(DB) + ra + ((FI0) + 1) * 1024 + ca1]; \
        STMT                                                               \
        __builtin_amdgcn_s_setprio(1);                                     \
        _Pragma("unroll")                                                  \
        for (int fj = 0; fj < 4; fj++) {                                   \
            acc[FI0][fj] = __builtin_amdgcn_mfma_f32_16x16x32_bf16(        \
                af00, bfr[fj][0], acc[FI0][fj], 0, 0, 0);                  \
            acc[FI0][fj] = __builtin_amdgcn_mfma_f32_16x16x32_bf16(        \
                af01, bfr[fj][1], acc[FI0][fj], 0, 0, 0);                  \
            acc[(FI0) + 1][fj] = __builtin_amdgcn_mfma_f32_16x16x32_bf16(  \
                af10, bfr[fj][0], acc[(FI0) + 1][fj], 0, 0, 0);            \
            acc[(FI0) + 1][fj] = __builtin_amdgcn_mfma_f32_16x16x32_bf16(  \
                af11, bfr[fj][1], acc[(FI0) + 1][fj], 0, 0, 0);            \
        }                                                                  \
        __builtin_amdgcn_s_setprio(0);                                     \
        WAITST                                                             \
        __builtin_amdgcn_sched_barrier(0);                                 \
        __builtin_amdgcn_s_barrier();                                      \
        __builtin_amdgcn_sched_barrier(0);                                 \
    } while (0)

    int NT = K >> 6;              // K-tiles of 64 (NT even, >= 4 here)
    int NITER = NT >> 1;

    // prologue: kt0 complete + kt1.B; wait for kt0, barrier.
    STG_A(0, 0, 0); STG_A(0, 1, 0);
    STG_B(0, 0, 0); STG_B(0, 1, 0);
    STG_B(32768, 0, 1); STG_B(32768, 1, 1);
    asm volatile("s_waitcnt vmcnt(4)" ::: "memory");
    __builtin_amdgcn_sched_barrier(0);
    __builtin_amdgcn_s_barrier();
    __builtin_amdgcn_sched_barrier(0);

    for (int j = 0; j < NITER; ++j) {
        int k1 = 2 * j + 1, k2 = 2 * j + 2, k3 = 2 * j + 3;
        bool nl = (j + 1 < NITER);
        DO_PHASE(0, 0, true, , STG_A(32768, 0, k1););
        DO_PHASE(0, 2, false, , STG_A(32768, 1, k1););
        DO_PHASE(0, 4, false, , if (nl) STG_B(0, 0, k2););
        DO_PHASE(0, 6, false,
                 if (nl) { asm volatile("s_waitcnt vmcnt(4)" ::: "memory"); }
                 else    { asm volatile("s_waitcnt vmcnt(0)" ::: "memory"); },
                 if (nl) STG_B(0, 1, k2););
        DO_PHASE(32768, 0, true, , if (nl) STG_A(0, 0, k2););
        DO_PHASE(32768, 2, false, , if (nl) STG_A(0, 1, k2););
        DO_PHASE(32768, 4, false, , if (nl) STG_B(32768, 0, k3););
        DO_PHASE(32768, 6, false,
                 if (nl) { asm volatile("s_waitcnt vmcnt(4)" ::: "memory"); },
                 if (nl) STG_B(32768, 1, k3););
    }
#undef DO_PHASE
#undef STG_A
#undef STG_B

    // epilogue: C/D layout col=lane&15, row=(lane>>4)*4+reg
    int cl = lr;
    float bv[4];
#pragma unroll
    for (int fj = 0; fj < 4; fj++)
        bv[fj] = BIAS ? G.bias[bn + (wn << 6) + (fj << 4) + cl] : 0.f;
#pragma unroll
    for (int fi = 0; fi < 8; fi++) {
        int row0 = bm + (wm << 7) + (fi << 4) + (q << 2);
#pragma unroll
        for (int r = 0; r < 4; r++) {
            size_t rowoff = (size_t)(row0 + r) * ldc;
#pragma unroll
            for (int fj = 0; fj < 4; fj++) {
                int col = bn + (wn << 6) + (fj << 4) + cl;
                float v = acc[fi][fj][r] + bv[fj];
                if (RELU) v = fmaxf(v, 0.f);
                if (OUTF32)
                    ((float*)G.C)[rowoff + col] = v;
                else
                    ((ushort*)G.C)[rowoff + col] = f2b(v);
            }
        }
    }
}

// ---------------------------------------------------------------------------
// Grouped mix pass 1 (F=256): T[b,i,f] = relu(sum_j adj[i,j]*T[b,j,f]+bias[f])
// 5 regions x 4096 blocks.
// ---------------------------------------------------------------------------
struct M1Desc { ushort* T; const float* adj; const float* bias; int nj; };
struct M1Params { M1Desc d[5]; };

template <int NJ>
__device__ __forceinline__ void mix1_body(ushort* base, const float* As, float bi) {
    float v[NJ];
#pragma unroll
    for (int j = 0; j < NJ; j++) v[j] = b2f(base[(size_t)j * 256]);
#pragma unroll
    for (int i = 0; i < NJ; i++) {
        float o = 0.f;
#pragma unroll
        for (int j = 0; j < NJ; j++) o += As[i * NJ + j] * v[j];
        base[(size_t)i * 256] = f2b(fmaxf(o + bi, 0.f));
    }
}

__global__ __launch_bounds__(256) void mixg1(M1Params P) {
    __shared__ float As[625];
    int r = blockIdx.x >> 12;
    const M1Desc& D = P.d[r];
    int t = threadIdx.x;
    int nj = D.nj;
    for (int i = t; i < nj * nj; i += 256) As[i] = D.adj[i];
    __syncthreads();
    int id = ((blockIdx.x & 4095) << 8) + t;
    int f = id & 255, b = id >> 8;
    ushort* base = D.T + ((size_t)b * nj) * 256 + f;
    float bi = D.bias[f];
    switch (nj) {
        case 25: mix1_body<25>(base, As, bi); break;
        case 5:  mix1_body<5>(base, As, bi); break;
        case 3:  mix1_body<3>(base, As, bi); break;
        default: mix1_body<6>(base, As, bi); break;
    }
}

// ---------------------------------------------------------------------------
// Grouped mix pass 2 (F=512): scatter-form. Region 0: global in-place mix on
// XGL even half (sldr=1024, jm=identity). Regions 1-4: part mix P3 -> XGL
// odd half via joint map. 5 regions x 8192 blocks.
// ---------------------------------------------------------------------------
struct M2Desc {
    const ushort* src; ushort* dst; const float* adj; const float* bias;
    int nj, sldr; int jm[25];
};
struct M2Params { M2Desc d[5]; };

template <int NJ>
__device__ __forceinline__ void mix2_body(const ushort* src, int sldr, ushort* dst,
                                          const int* jms, const float* As, float bi) {
    float v[NJ];
#pragma unroll
    for (int j = 0; j < NJ; j++) v[j] = b2f(src[(size_t)j * sldr]);
#pragma unroll
    for (int i = 0; i < NJ; i++) {
        float o = 0.f;
#pragma unroll
        for (int j = 0; j < NJ; j++) o += As[i * NJ + j] * v[j];
        dst[(size_t)jms[i] * 1024] = f2b(fmaxf(o + bi, 0.f));
    }
}

__global__ __launch_bounds__(256) void mixg2(M2Params P) {
    __shared__ float As[625];
    __shared__ int jms[25];
    int r = blockIdx.x >> 13;
    const M2Desc& D = P.d[r];
    int t = threadIdx.x;
    int nj = D.nj;
    for (int i = t; i < nj * nj; i += 256) As[i] = D.adj[i];
    if (t < nj) jms[t] = D.jm[t];
    __syncthreads();
    int id = ((blockIdx.x & 8191) << 8) + t;
    int f = id & 511, b = id >> 9;
    const ushort* src = D.src + ((size_t)b * nj) * D.sldr + f;
    ushort* dst = D.dst + (size_t)b * 25 * 1024 + f;
    float bi = D.bias[f];
    switch (nj) {
        case 25: mix2_body<25>(src, D.sldr, dst, jms, As, bi); break;
        case 5:  mix2_body<5>(src, D.sldr, dst, jms, As, bi); break;
        case 3:  mix2_body<3>(src, D.sldr, dst, jms, As, bi); break;
        default: mix2_body<6>(src, D.sldr, dst, jms, As, bi); break;
    }
}

// ---------------------------------------------------------------------------
extern "C" void kernel_launch(void* const* d_in, const int* in_sizes, int n_in,
                              void* d_out, int out_size, void* d_ws,
                              size_t ws_size, hipStream_t stream) {
    const float* x    = (const float*)d_in[0];
    const float* adjg = (const float*)d_in[1];
    const float* al0  = (const float*)d_in[2];
    const float* al2  = (const float*)d_in[4];
    const float* al3  = (const float*)d_in[5];
    const float* al4  = (const float*)d_in[6];
    const float* Wg0  = (const float*)d_in[7];
    const float* bg0  = (const float*)d_in[8];
    const float* Wg1  = (const float*)d_in[9];
    const float* bg1  = (const float*)d_in[10];
    const float* Wf0  = (const float*)d_in[31];
    const float* bf0  = (const float*)d_in[32];
    const float* Wf1  = (const float*)d_in[33];
    const float* bf1  = (const float*)d_in[34];

    float* ws = (float*)d_ws;
    float* ADJ = ws;                               // 4096 floats
    ushort* U   = (ushort*)(ws + 4096);
    ushort* Xb  = U;                               // 52.4M (a-pass input)
    ushort* XGL = Xb + (size_t)SZ_FULL;            // 104.9M: [XG | XL] per row
    ushort* T   = XGL + (size_t)MROWS * 1024;      // 26.2M
    ushort* P1  = T + (size_t)MROWS * 256;         // 17.8M (B*17*256)
    ushort* Wb  = P1 + (size_t)BATCH * 17 * 256;   // 2.1M weights
    ushort* P3  = Xb;                              // 35.7M, reuses dead Xb
    ushort* HF  = Xb;                              // fusion hidden, reuses Xb

    ushort* Wg0t = Wb;                             // [256][512]
    ushort* Wg1t = Wb + 131072;                    // [512][256]
    ushort* Wf0t = Wb + 262144;                    // [512][1024]
    ushort* Wf1t = Wb + 786432;                    // [512][512]
    ushort* Wpt  = Wb + 1048576;                   // 4x (Wat 131072 + Wbt 131072)

    struct Part { int n, widx; int idx[6]; };
    const Part parts[4] = {
        {5, 11, {0, 1, 2, 3, 4, 0}},
        {3, 19, {5, 7, 9, 0, 0, 0}},
        {3, 23, {6, 8, 10, 0, 0, 0}},
        {6, 27, {11, 12, 13, 14, 15, 16}},
    };
    const int cumn[4] = {0, 5, 8, 11};

    dim3 blk(256), blk512(512);

    adjnorm_kernel<<<1, blk, 0, stream>>>(adjg, al0, al2, al3, al4, ADJ);
    cvt_bf16<<<SZ_FULL / 4 / 256, blk, 0, stream>>>(x, Xb, SZ_FULL / 4);
    zero_tail<<<16384, blk, 0, stream>>>(XGL);

    // grouped weight transposes (12 regions, 2048 blocks)
    {
        WParams WP{};
        int e = 0, i = 0;
        auto add = [&](const float* W, ushort* Wt, int K, int N) {
            int nx = N >> 5;
            int nxlog = (nx == 8) ? 3 : ((nx == 16) ? 4 : 5);
            e += nx * (K >> 5);
            WP.d[i++] = {W, Wt, K, N, nxlog, e};
        };
        add(Wg0, Wg0t, 512, 256);
        add(Wg1, Wg1t, 256, 512);
        add(Wf0, Wf0t, 1024, 512);
        add(Wf1, Wf1t, 512, 512);
        for (int qv = 0; qv < 4; qv++) {
            add((const float*)d_in[parts[qv].widx], Wpt + qv * 262144, 512, 256);
            add((const float*)d_in[parts[qv].widx + 2], Wpt + qv * 262144 + 131072, 256, 512);
        }
        wtrans_all<<<2048, blk, 0, stream>>>(WP);
    }

    auto setg = [](GDesc& g, const ushort* A, const ushort* Wt, const float* bias,
                   void* C, int K, int lda, int ldc, int nT, int wgEnd, int gn,
                   int flags, const int* map) {
        g.A = A; g.Wt = Wt; g.bias = bias; g.C = C; g.K = K; g.lda = lda;
        g.ldc = ldc; g.nTiles = nT; g.wgEnd = wgEnd; g.gn = gn; g.flags = flags;
        g.pad = 0;
        for (int i = 0; i < 6; i++) g.gmap[i] = map ? map[i] : 0;
    };

    // ---- a-pass: global (400 wg) + 4 local parts (272 wg) = 672 wg ----
    {
        GParams GA{};
        int e = 400;
        setg(GA.g[0], Xb, Wg0t, nullptr, T, 512, 512, 256, 1, e, 0, 0, nullptr);
        for (int qv = 0; qv < 4; qv++) {
            e += parts[qv].n * 16;
            setg(GA.g[1 + qv], Xb, Wpt + qv * 262144, nullptr,
                 P1 + (size_t)BATCH * cumn[qv] * 256,
                 512, 512, 256, 1, e, parts[qv].n, 1, parts[qv].idx);
        }
        gemmg<<<672, blk512, 0, stream>>>(GA);
    }

    // ---- mix pass 1 (F=256): global T + 4 parts P1 ----
    {
        M1Params M1{};
        M1.d[0] = {T, ADJ, bg0, 25};
        for (int qv = 0; qv < 4; qv++)
            M1.d[1 + qv] = {P1 + (size_t)BATCH * cumn[qv] * 256,
                            ADJ + 640 + qv * 64,
                            (const float*)d_in[parts[qv].widx + 1],
                            parts[qv].n};
        mixg1<<<20480, blk, 0, stream>>>(M1);
    }

    // ---- b-pass: global (800 wg) + 4 local parts (544 wg) = 1344 wg ----
    {
        GParams GB{};
        int e = 800;
        setg(GB.g[0], T, Wg1t, nullptr, XGL, 256, 256, 1024, 2, e, 0, 0, nullptr);
        for (int qv = 0; qv < 4; qv++) {
            e += parts[qv].n * 32;
            setg(GB.g[1 + qv], P1 + (size_t)BATCH * cumn[qv] * 256,
                 Wpt + qv * 262144 + 131072, nullptr,
                 P3 + (size_t)BATCH * cumn[qv] * 512,
                 256, 256, 512, 2, e, 0, 0, nullptr);
        }
        gemmg<<<1344, blk512, 0, stream>>>(GB);
    }

    // ---- mix pass 2 (F=512): global XGL in-place + 4 part scatters ----
    {
        M2Params M2{};
        M2.d[0].src = XGL; M2.d[0].dst = XGL; M2.d[0].adj = ADJ;
        M2.d[0].bias = bg1; M2.d[0].nj = 25; M2.d[0].sldr = 1024;
        for (int i = 0; i < 25; i++) M2.d[0].jm[i] = i;
        for (int qv = 0; qv < 4; qv++) {
            M2Desc& D = M2.d[1 + qv];
            D.src = P3 + (size_t)BATCH * cumn[qv] * 512;
            D.dst = XGL + 512;
            D.adj = ADJ + 640 + qv * 64;
            D.bias = (const float*)d_in[parts[qv].widx + 3];
            D.nj = parts[qv].n; D.sldr = 512;
            for (int i = 0; i < 25; i++) D.jm[i] = (i < 6) ? parts[qv].idx[i] : 0;
        }
        mixg2<<<40960, blk, 0, stream>>>(M2);
    }

    // ---- fusion: HF = relu(XGL @ Wf0 + bf0); out = HF @ Wf1 + bf1 (f32) ----
    {
        GParams GF{};
        setg(GF.g[0], XGL, Wf0t, bf0, HF, 1024, 1024, 512, 2, 800, 0, 2 | 4, nullptr);
        gemmg<<<800, blk512, 0, stream>>>(GF);
    }
    {
        GParams GO{};
        setg(GO.g[0], HF, Wf1t, bf1, d_out, 512, 512, 512, 2, 800, 0, 2 | 8, nullptr);
        gemmg<<<800, blk512, 0, stream>>>(GO);
    }

    (void)in_sizes; (void)n_in; (void)out_size; (void)ws_size;
}

// Round 10
// 895.472 us; speedup vs baseline: 1.1388x; 1.0683x over previous
//
#include <hip/hip_runtime.h>

// ---------------------------------------------------------------------------
// GLA_GCN bf16-MFMA pipeline. B=4096, J=25, D_IN=512, D_H=256, D_OUT=512.
// Partition 1 is dead (all its joints overwritten by parts 2/3/4).
// GEMMs are GROUPED: one dispatch for all five "a" GEMMs (672 wg), one for
// all five "b" GEMMs (1344 wg), plus Wf0/Wf1 (800 wg each).
// GEMM inner loop: 256x256 tile, BK=64, 8 waves, 8-phase/iter schedule,
// ONE barrier per phase (single-barrier invariant: every stage overwrites a
// slot last read >=2 phases back; every buffer's covering vmcnt-wait is
// barrier-separated from its first read), counted vmcnt(4) at P3/P7
// (vmcnt(0) only at last-iter P3), 2dbuf x 4 half-tile LDS (128 KiB),
// chunk-XOR swizzle (bank-conflict-free ds_read_b128), compiler-managed
// lgkm waits, setprio around MFMA, sched_barrier(0) fences around each
// s_barrier, XCD block swizzle.
// MIX kernels: adjacency is wave-uniform -> read via scalar pipe (uniform
// global loads, s_load from K$), NOT LDS broadcast (625 ds_read_b32/thread
// was LDS-issue-bound); 2 f-elements per thread as float2 (packed f32 FMA).
// XG|XL stored interleaved per row (XGL, lda=1024) so fusion GEMM is plain.
// ---------------------------------------------------------------------------

#define BATCH 4096
#define NJOINT 25
#define MROWS (BATCH * NJOINT)          // 102400
#define SZ_FULL (MROWS * 512)           // 52,428,800 bf16 elements

typedef __attribute__((ext_vector_type(8))) short short8;
typedef __attribute__((ext_vector_type(4))) float float4_;

__device__ __forceinline__ float b2f(ushort u) {
    union { float f; uint32_t i; } x; x.i = ((uint32_t)u) << 16; return x.f;
}
__device__ __forceinline__ ushort f2b(float f) {
    union { float f; uint32_t i; } x; x.f = f;
    uint32_t r = x.i + 0x7fff + ((x.i >> 16) & 1);
    return (ushort)(r >> 16);
}
__device__ __forceinline__ void async16(const void* g, void* l) {
    __builtin_amdgcn_global_load_lds(
        (const __attribute__((address_space(1))) void*)g,
        (__attribute__((address_space(3))) void*)l, 16, 0, 0);
}

// ---------------------------------------------------------------------------
// Adjacency normalization (fp32, tiny)
// ---------------------------------------------------------------------------
__device__ void norm_one(const float* A, int n, float* out, float* sAdj, float* sD) {
    int t = threadIdx.x;
    for (int i = t; i < n * n; i += 256) sAdj[i] = A[i];
    __syncthreads();
    if (t < n) {
        float s = 0.f;
        for (int j = 0; j < n; j++) s += sAdj[t * n + j];
        sD[t] = 1.0f / sqrtf(fmaxf(s, 1e-6f));
    }
    __syncthreads();
    for (int i = t; i < n * n; i += 256) {
        int r = i / n, c = i % n;
        out[i] = sD[r] * sAdj[i] * sD[c];
    }
    __syncthreads();
}

__global__ __launch_bounds__(256) void adjnorm_kernel(
    const float* Ag, const float* A0, const float* A2, const float* A3,
    const float* A4, float* ADJ) {
    __shared__ float sAdj[640];
    __shared__ float sD[32];
    norm_one(Ag, 25, ADJ, sAdj, sD);
    norm_one(A0, 5, ADJ + 640 + 0 * 64, sAdj, sD);
    norm_one(A2, 3, ADJ + 640 + 1 * 64, sAdj, sD);
    norm_one(A3, 3, ADJ + 640 + 2 * 64, sAdj, sD);
    norm_one(A4, 6, ADJ + 640 + 3 * 64, sAdj, sD);
}

// ---------------------------------------------------------------------------
// fp32 -> bf16 convert (x), float4 -> ushort4
// ---------------------------------------------------------------------------
__global__ __launch_bounds__(256) void cvt_bf16(const float* __restrict__ in,
                                                ushort* __restrict__ out, int n4) {
    int id = blockIdx.x * 256 + threadIdx.x;
    if (id < n4) {
        float4 v = ((const float4*)in)[id];
        ushort4 o;
        o.x = f2b(v.x); o.y = f2b(v.y); o.z = f2b(v.z); o.w = f2b(v.w);
        ((ushort4*)out)[id] = o;
    }
}

// ---------------------------------------------------------------------------
// Grouped weight transpose: W fp32 [K][N] -> Wt bf16 [N][K], 12 regions.
// ---------------------------------------------------------------------------
struct WDesc { const float* W; ushort* Wt; int K, N, nxlog, end; };
struct WParams { WDesc d[12]; };

__global__ __launch_bounds__(256) void wtrans_all(WParams P) {
    __shared__ float tile[32][33];
    int bid = blockIdx.x;
    int i = 0, start = 0;
    while (bid >= P.d[i].end) { start = P.d[i].end; i++; }
    const WDesc& D = P.d[i];
    int local = bid - start;
    int bx = local & ((1 << D.nxlog) - 1);
    int by = local >> D.nxlog;
    int K = D.K, N = D.N;
    int t = threadIdx.x, tx = t & 31, ty = t >> 5;
    int k0 = by * 32, n0 = bx * 32;
    for (int r = ty; r < 32; r += 8)
        tile[r][tx] = D.W[(size_t)(k0 + r) * N + n0 + tx];
    __syncthreads();
    for (int r = ty; r < 32; r += 8)
        D.Wt[(size_t)(n0 + r) * K + k0 + tx] = f2b(tile[tx][r]);
}

// ---------------------------------------------------------------------------
// Zero XL joints 17..24 in XGL interleaved layout (row stride 1024, XL at +512)
// ---------------------------------------------------------------------------
__global__ __launch_bounds__(256) void zero_tail(ushort* __restrict__ XGL) {
    int id = blockIdx.x * 256 + threadIdx.x;
    int f4 = id & 127;
    int rj = (id >> 7) & 7;
    int b = id >> 10;
    ushort4 z; z.x = 0; z.y = 0; z.z = 0; z.w = 0;
    ((ushort4*)(XGL + ((size_t)(b * 25 + 17 + rj) * 1024 + 512)))[f4] = z;
}

// ---------------------------------------------------------------------------
// Grouped bf16 MFMA GEMM, 8-phase schedule, ONE barrier per phase.
//   (unchanged from R8 — see header comment)
// ---------------------------------------------------------------------------
struct GDesc {
    const ushort* A; const ushort* Wt; const float* bias; void* C;
    int K, lda, ldc, nTiles, wgEnd, gn, flags, pad;
    int gmap[6];
};
struct GParams { GDesc g[5]; };

__global__ __launch_bounds__(512, 2) void gemmg(GParams P) {
    __shared__ ushort lds[65536];   // 128 KiB: [2 dbuf][4 slots][8192]
    int t = threadIdx.x;
    int l = t & 63, w = t >> 6;

    // bijective XCD swizzle (all grids are multiples of 8)
    int nwg = (int)gridDim.x;
    int cpx = nwg >> 3;
    int wg = ((int)blockIdx.x & 7) * cpx + ((int)blockIdx.x >> 3);

    int gi = 0, wg0 = 0;
    while (wg >= P.g[gi].wgEnd) { wg0 = P.g[gi].wgEnd; gi++; }
    const GDesc& G = P.g[gi];
    int lw = wg - wg0;
    int tm, tn;
    if (G.nTiles == 2) { tm = lw >> 1; tn = lw & 1; }
    else               { tm = lw;      tn = 0; }
    int bm = tm << 8, bn = tn << 8;
    const int K = G.K, lda = G.lda, ldc = G.ldc;
    const bool GATHER = (G.flags & 1) != 0;
    const bool BIAS   = (G.flags & 2) != 0;
    const bool RELU   = (G.flags & 4) != 0;
    const bool OUTF32 = (G.flags & 8) != 0;

    // staging: lane l covers row (l>>3), linear chunk (l&7); source chunk
    // pre-swizzled by ^(row&7) = ^(l>>3)
    int srow = (w << 4) + (l >> 3);
    int sch = ((l & 7) ^ (l >> 3)) << 3;
    const ushort* pA[2][2];
    const ushort* pB[2][2];
#pragma unroll
    for (int h = 0; h < 2; h++)
#pragma unroll
        for (int i = 0; i < 2; i++) {
            int r = bm + h * 128 + srow + i * 8;
            if (GATHER) { int b = r / G.gn; r = b * 25 + G.gmap[r - b * G.gn]; }
            pA[h][i] = G.A + (size_t)r * lda + sch;
            int c = bn + h * 128 + srow + i * 8;
            pB[h][i] = G.Wt + (size_t)c * K + sch;
        }
    int stga = w << 10;

    // fragment read offsets
    int wm = w >> 2, wn = w & 3;
    int lr = l & 15, q = l >> 4;
    int cx = lr & 7;
    int ca0 = (q ^ cx) << 3;
    int ca1 = ca0 ^ 32;
    int ra = (wm << 13) + (lr << 6);
    int rb = 16384 + ((wn >> 1) << 13) + ((wn & 1) << 12) + (lr << 6);

    float4_ acc[8][4];
#pragma unroll
    for (int fi = 0; fi < 8; fi++)
#pragma unroll
        for (int fj = 0; fj < 4; fj++) acc[fi][fj] = (float4_)0.f;
    short8 bfr[4][2];

#define STG_A(DB, H, KT) do {                                              \
        async16(pA[H][0] + (KT) * 64, &lds[(DB) + (H) * 8192 + stga]);     \
        async16(pA[H][1] + (KT) * 64, &lds[(DB) + (H) * 8192 + stga + 512]); \
    } while (0)
#define STG_B(DB, H, KT) do {                                              \
        async16(pB[H][0] + (KT) * 64, &lds[(DB) + 16384 + (H) * 8192 + stga]); \
        async16(pB[H][1] + (KT) * 64, &lds[(DB) + 16384 + (H) * 8192 + stga + 512]); \
    } while (0)

#define DO_PHASE(DB, FI0, RDB, WAITST, STMT) do {                          \
        short8 af00, af01, af10, af11;                                     \
        if (RDB) {                                                         \
            _Pragma("unroll")                                              \
            for (int fj = 0; fj < 4; fj++) {                               \
                bfr[fj][0] = *(const short8*)&lds[(DB) + rb + fj * 1024 + ca0]; \
                bfr[fj][1] = *(const short8*)&lds[(DB) + rb + fj * 1024 + ca1]; \
            }                                                              \
        }                                                                  \
        af00 = *(const short8*)&lds[(DB) + ra + (FI0) * 1024 + ca0];       \
        af01 = *(const short8*)&lds[(DB) + ra + (FI0) * 1024 + ca1];       \
        af10 = *(const short8*)&lds[(DB) + ra + ((FI0) + 1) * 1024 + ca0]; \
        af11 = *(const short8*)&lds[(DB) + ra + ((FI0) + 1) * 1024 + ca1]; \
        STMT                                                               \
        __builtin_amdgcn_s_setprio(1);                                     \
        _Pragma("unroll")                                                  \
        for (int fj = 0; fj < 4; fj++) {                                   \
            acc[FI0][fj] = __builtin_amdgcn_mfma_f32_16x16x32_bf16(        \
                af00, bfr[fj][0], acc[FI0][fj], 0, 0, 0);                  \
            acc[FI0][fj] = __builtin_amdgcn_mfma_f32_16x16x32_bf16(        \
                af01, bfr[fj][1], acc[FI0][fj], 0, 0, 0);                  \
            acc[(FI0) + 1][fj] = __builtin_amdgcn_mfma_f32_16x16x32_bf16(  \
                af10, bfr[fj][0], acc[(FI0) + 1][fj], 0, 0, 0);            \
            acc[(FI0) + 1][fj] = __builtin_amdgcn_mfma_f32_16x16x32_bf16(  \
                af11, bfr[fj][1], acc[(FI0) + 1][fj], 0, 0, 0);            \
        }                                                                  \
        __builtin_amdgcn_s_setprio(0);                                     \
        WAITST                                                             \
        __builtin_amdgcn_sched_barrier(0);                                 \
        __builtin_amdgcn_s_barrier();                                      \
        __builtin_amdgcn_sched_barrier(0);                                 \
    } while (0)

    int NT = K >> 6;              // K-tiles of 64 (NT even, >= 4 here)
    int NITER = NT >> 1;

    // prologue: kt0 complete + kt1.B; wait for kt0, barrier.
    STG_A(0, 0, 0); STG_A(0, 1, 0);
    STG_B(0, 0, 0); STG_B(0, 1, 0);
    STG_B(32768, 0, 1); STG_B(32768, 1, 1);
    asm volatile("s_waitcnt vmcnt(4)" ::: "memory");
    __builtin_amdgcn_sched_barrier(0);
    __builtin_amdgcn_s_barrier();
    __builtin_amdgcn_sched_barrier(0);

    for (int j = 0; j < NITER; ++j) {
        int k1 = 2 * j + 1, k2 = 2 * j + 2, k3 = 2 * j + 3;
        bool nl = (j + 1 < NITER);
        DO_PHASE(0, 0, true, , STG_A(32768, 0, k1););
        DO_PHASE(0, 2, false, , STG_A(32768, 1, k1););
        DO_PHASE(0, 4, false, , if (nl) STG_B(0, 0, k2););
        DO_PHASE(0, 6, false,
                 if (nl) { asm volatile("s_waitcnt vmcnt(4)" ::: "memory"); }
                 else    { asm volatile("s_waitcnt vmcnt(0)" ::: "memory"); },
                 if (nl) STG_B(0, 1, k2););
        DO_PHASE(32768, 0, true, , if (nl) STG_A(0, 0, k2););
        DO_PHASE(32768, 2, false, , if (nl) STG_A(0, 1, k2););
        DO_PHASE(32768, 4, false, , if (nl) STG_B(32768, 0, k3););
        DO_PHASE(32768, 6, false,
                 if (nl) { asm volatile("s_waitcnt vmcnt(4)" ::: "memory"); },
                 if (nl) STG_B(32768, 1, k3););
    }
#undef DO_PHASE
#undef STG_A
#undef STG_B

    // epilogue: C/D layout col=lane&15, row=(lane>>4)*4+reg
    int cl = lr;
    float bv[4];
#pragma unroll
    for (int fj = 0; fj < 4; fj++)
        bv[fj] = BIAS ? G.bias[bn + (wn << 6) + (fj << 4) + cl] : 0.f;
#pragma unroll
    for (int fi = 0; fi < 8; fi++) {
        int row0 = bm + (wm << 7) + (fi << 4) + (q << 2);
#pragma unroll
        for (int r = 0; r < 4; r++) {
            size_t rowoff = (size_t)(row0 + r) * ldc;
#pragma unroll
            for (int fj = 0; fj < 4; fj++) {
                int col = bn + (wn << 6) + (fj << 4) + cl;
                float v = acc[fi][fj][r] + bv[fj];
                if (RELU) v = fmaxf(v, 0.f);
                if (OUTF32)
                    ((float*)G.C)[rowoff + col] = v;
                else
                    ((ushort*)G.C)[rowoff + col] = f2b(v);
            }
        }
    }
}

// ---------------------------------------------------------------------------
// Grouped mix pass 1 (F=256): T[b,i,f] = relu(sum_j adj[i,j]*T[b,j,f]+bias[f])
// Adjacency read via UNIFORM global loads (scalar pipe, K$-cached) — no LDS.
// 2 f-elements per thread (float2). 5 regions x 2048 blocks.
// ---------------------------------------------------------------------------
struct M1Desc { ushort* T; const float* adj; const float* bias; int nj; };
struct M1Params { M1Desc d[5]; };

template <int NJ>
__device__ __forceinline__ void mix1_body(ushort* base, const float* __restrict__ adj,
                                          float bx, float by) {
    float vx[NJ], vy[NJ];
#pragma unroll
    for (int j = 0; j < NJ; j++) {
        uint u = *(const uint*)&base[(size_t)j * 256];
        vx[j] = b2f((ushort)(u & 0xffff));
        vy[j] = b2f((ushort)(u >> 16));
    }
#pragma unroll
    for (int i = 0; i < NJ; i++) {
        float ox = 0.f, oy = 0.f;
#pragma unroll
        for (int j = 0; j < NJ; j++) {
            float a = adj[i * NJ + j];        // uniform -> s_load
            ox += a * vx[j]; oy += a * vy[j];
        }
        ox = fmaxf(ox + bx, 0.f); oy = fmaxf(oy + by, 0.f);
        uint r = (uint)f2b(ox) | ((uint)f2b(oy) << 16);
        *(uint*)&base[(size_t)i * 256] = r;
    }
}

__global__ __launch_bounds__(256) void mixg1(M1Params P) {
    int r = blockIdx.x >> 11;                  // 2048 blocks per region
    const M1Desc& D = P.d[r];
    int t = threadIdx.x;
    int id = ((blockIdx.x & 2047) << 8) + t;   // B * 128 elements
    int f2 = id & 127, b = id >> 7;
    ushort* base = D.T + ((size_t)b * D.nj) * 256 + 2 * f2;
    float bx = D.bias[2 * f2], by = D.bias[2 * f2 + 1];
    switch (D.nj) {
        case 25: mix1_body<25>(base, D.adj, bx, by); break;
        case 5:  mix1_body<5>(base, D.adj, bx, by); break;
        case 3:  mix1_body<3>(base, D.adj, bx, by); break;
        default: mix1_body<6>(base, D.adj, bx, by); break;
    }
}

// ---------------------------------------------------------------------------
// Grouped mix pass 2 (F=512): scatter-form. Region 0: global in-place mix on
// XGL even half (sldr=1024, jm=identity). Regions 1-4: part mix P3 -> XGL
// odd half via joint map. Uniform scalar adjacency/jm reads; float2 per
// thread. 5 regions x 4096 blocks.
// ---------------------------------------------------------------------------
struct M2Desc {
    const ushort* src; ushort* dst; const float* adj; const float* bias;
    int nj, sldr; int jm[25];
};
struct M2Params { M2Desc d[5]; };

template <int NJ>
__device__ __forceinline__ void mix2_body(const ushort* src, int sldr, ushort* dst,
                                          const int* __restrict__ jms,
                                          const float* __restrict__ adj,
                                          float bx, float by) {
    float vx[NJ], vy[NJ];
#pragma unroll
    for (int j = 0; j < NJ; j++) {
        uint u = *(const uint*)&src[(size_t)j * sldr];
        vx[j] = b2f((ushort)(u & 0xffff));
        vy[j] = b2f((ushort)(u >> 16));
    }
#pragma unroll
    for (int i = 0; i < NJ; i++) {
        float ox = 0.f, oy = 0.f;
#pragma unroll
        for (int j = 0; j < NJ; j++) {
            float a = adj[i * NJ + j];        // uniform -> s_load
            ox += a * vx[j]; oy += a * vy[j];
        }
        ox = fmaxf(ox + bx, 0.f); oy = fmaxf(oy + by, 0.f);
        uint r = (uint)f2b(ox) | ((uint)f2b(oy) << 16);
        *(uint*)&dst[(size_t)jms[i] * 1024] = r;
    }
}

__global__ __launch_bounds__(256) void mixg2(M2Params P) {
    int r = blockIdx.x >> 12;                  // 4096 blocks per region
    const M2Desc& D = P.d[r];
    int t = threadIdx.x;
    int id = ((blockIdx.x & 4095) << 8) + t;   // B * 256 elements
    int f2 = id & 255, b = id >> 8;
    const ushort* src = D.src + ((size_t)b * D.nj) * D.sldr + 2 * f2;
    ushort* dst = D.dst + (size_t)b * 25 * 1024 + 2 * f2;
    float bx = D.bias[2 * f2], by = D.bias[2 * f2 + 1];
    switch (D.nj) {
        case 25: mix2_body<25>(src, D.sldr, dst, D.jm, D.adj, bx, by); break;
        case 5:  mix2_body<5>(src, D.sldr, dst, D.jm, D.adj, bx, by); break;
        case 3:  mix2_body<3>(src, D.sldr, dst, D.jm, D.adj, bx, by); break;
        default: mix2_body<6>(src, D.sldr, dst, D.jm, D.adj, bx, by); break;
    }
}

// ---------------------------------------------------------------------------
extern "C" void kernel_launch(void* const* d_in, const int* in_sizes, int n_in,
                              void* d_out, int out_size, void* d_ws,
                              size_t ws_size, hipStream_t stream) {
    const float* x    = (const float*)d_in[0];
    const float* adjg = (const float*)d_in[1];
    const float* al0  = (const float*)d_in[2];
    const float* al2  = (const float*)d_in[4];
    const float* al3  = (const float*)d_in[5];
    const float* al4  = (const float*)d_in[6];
    const float* Wg0  = (const float*)d_in[7];
    const float* bg0  = (const float*)d_in[8];
    const float* Wg1  = (const float*)d_in[9];
    const float* bg1  = (const float*)d_in[10];
    const float* Wf0  = (const float*)d_in[31];
    const float* bf0  = (const float*)d_in[32];
    const float* Wf1  = (const float*)d_in[33];
    const float* bf1  = (const float*)d_in[34];

    float* ws = (float*)d_ws;
    float* ADJ = ws;                               // 4096 floats
    ushort* U   = (ushort*)(ws + 4096);
    ushort* Xb  = U;                               // 52.4M (a-pass input)
    ushort* XGL = Xb + (size_t)SZ_FULL;            // 104.9M: [XG | XL] per row
    ushort* T   = XGL + (size_t)MROWS * 1024;      // 26.2M
    ushort* P1  = T + (size_t)MROWS * 256;         // 17.8M (B*17*256)
    ushort* Wb  = P1 + (size_t)BATCH * 17 * 256;   // 2.1M weights
    ushort* P3  = Xb;                              // 35.7M, reuses dead Xb
    ushort* HF  = Xb;                              // fusion hidden, reuses Xb

    ushort* Wg0t = Wb;                             // [256][512]
    ushort* Wg1t = Wb + 131072;                    // [512][256]
    ushort* Wf0t = Wb + 262144;                    // [512][1024]
    ushort* Wf1t = Wb + 786432;                    // [512][512]
    ushort* Wpt  = Wb + 1048576;                   // 4x (Wat 131072 + Wbt 131072)

    struct Part { int n, widx; int idx[6]; };
    const Part parts[4] = {
        {5, 11, {0, 1, 2, 3, 4, 0}},
        {3, 19, {5, 7, 9, 0, 0, 0}},
        {3, 23, {6, 8, 10, 0, 0, 0}},
        {6, 27, {11, 12, 13, 14, 15, 16}},
    };
    const int cumn[4] = {0, 5, 8, 11};

    dim3 blk(256), blk512(512);

    adjnorm_kernel<<<1, blk, 0, stream>>>(adjg, al0, al2, al3, al4, ADJ);
    cvt_bf16<<<SZ_FULL / 4 / 256, blk, 0, stream>>>(x, Xb, SZ_FULL / 4);
    zero_tail<<<16384, blk, 0, stream>>>(XGL);

    // grouped weight transposes (12 regions, 2048 blocks)
    {
        WParams WP{};
        int e = 0, i = 0;
        auto add = [&](const float* W, ushort* Wt, int K, int N) {
            int nx = N >> 5;
            int nxlog = (nx == 8) ? 3 : ((nx == 16) ? 4 : 5);
            e += nx * (K >> 5);
            WP.d[i++] = {W, Wt, K, N, nxlog, e};
        };
        add(Wg0, Wg0t, 512, 256);
        add(Wg1, Wg1t, 256, 512);
        add(Wf0, Wf0t, 1024, 512);
        add(Wf1, Wf1t, 512, 512);
        for (int qv = 0; qv < 4; qv++) {
            add((const float*)d_in[parts[qv].widx], Wpt + qv * 262144, 512, 256);
            add((const float*)d_in[parts[qv].widx + 2], Wpt + qv * 262144 + 131072, 256, 512);
        }
        wtrans_all<<<2048, blk, 0, stream>>>(WP);
    }

    auto setg = [](GDesc& g, const ushort* A, const ushort* Wt, const float* bias,
                   void* C, int K, int lda, int ldc, int nT, int wgEnd, int gn,
                   int flags, const int* map) {
        g.A = A; g.Wt = Wt; g.bias = bias; g.C = C; g.K = K; g.lda = lda;
        g.ldc = ldc; g.nTiles = nT; g.wgEnd = wgEnd; g.gn = gn; g.flags = flags;
        g.pad = 0;
        for (int i = 0; i < 6; i++) g.gmap[i] = map ? map[i] : 0;
    };

    // ---- a-pass: global (400 wg) + 4 local parts (272 wg) = 672 wg ----
    {
        GParams GA{};
        int e = 400;
        setg(GA.g[0], Xb, Wg0t, nullptr, T, 512, 512, 256, 1, e, 0, 0, nullptr);
        for (int qv = 0; qv < 4; qv++) {
            e += parts[qv].n * 16;
            setg(GA.g[1 + qv], Xb, Wpt + qv * 262144, nullptr,
                 P1 + (size_t)BATCH * cumn[qv] * 256,
                 512, 512, 256, 1, e, parts[qv].n, 1, parts[qv].idx);
        }
        gemmg<<<672, blk512, 0, stream>>>(GA);
    }

    // ---- mix pass 1 (F=256): global T + 4 parts P1; 5 x 2048 blocks ----
    {
        M1Params M1{};
        M1.d[0] = {T, ADJ, bg0, 25};
        for (int qv = 0; qv < 4; qv++)
            M1.d[1 + qv] = {P1 + (size_t)BATCH * cumn[qv] * 256,
                            ADJ + 640 + qv * 64,
                            (const float*)d_in[parts[qv].widx + 1],
                            parts[qv].n};
        mixg1<<<10240, blk, 0, stream>>>(M1);
    }

    // ---- b-pass: global (800 wg) + 4 local parts (544 wg) = 1344 wg ----
    {
        GParams GB{};
        int e = 800;
        setg(GB.g[0], T, Wg1t, nullptr, XGL, 256, 256, 1024, 2, e, 0, 0, nullptr);
        for (int qv = 0; qv < 4; qv++) {
            e += parts[qv].n * 32;
            setg(GB.g[1 + qv], P1 + (size_t)BATCH * cumn[qv] * 256,
                 Wpt + qv * 262144 + 131072, nullptr,
                 P3 + (size_t)BATCH * cumn[qv] * 512,
                 256, 256, 512, 2, e, 0, 0, nullptr);
        }
        gemmg<<<1344, blk512, 0, stream>>>(GB);
    }

    // ---- mix pass 2 (F=512): global XGL in-place + 4 part scatters ----
    {
        M2Params M2{};
        M2.d[0].src = XGL; M2.d[0].dst = XGL; M2.d[0].adj = ADJ;
        M2.d[0].bias = bg1; M2.d[0].nj = 25; M2.d[0].sldr = 1024;
        for (int i = 0; i < 25; i++) M2.d[0].jm[i] = i;
        for (int qv = 0; qv < 4; qv++) {
            M2Desc& D = M2.d[1 + qv];
            D.src = P3 + (size_t)BATCH * cumn[qv] * 512;
            D.dst = XGL + 512;
            D.adj = ADJ + 640 + qv * 64;
            D.bias = (const float*)d_in[parts[qv].widx + 3];
            D.nj = parts[qv].n; D.sldr = 512;
            for (int i = 0; i < 25; i++) D.jm[i] = (i < 6) ? parts[qv].idx[i] : 0;
        }
        mixg2<<<20480, blk, 0, stream>>>(M2);
    }

    // ---- fusion: HF = relu(XGL @ Wf0 + bf0); out = HF @ Wf1 + bf1 (f32) ----
    {
        GParams GF{};
        setg(GF.g[0], XGL, Wf0t, bf0, HF, 1024, 1024, 512, 2, 800, 0, 2 | 4, nullptr);
        gemmg<<<800, blk512, 0, stream>>>(GF);
    }
    {
        GParams GO{};
        setg(GO.g[0], HF, Wf1t, bf1, d_out, 512, 512, 512, 2, 800, 0, 2 | 8, nullptr);
        gemmg<<<800, blk512, 0, stream>>>(GO);
    }

    (void)in_sizes; (void)n_in; (void)out_size; (void)ws_size;
}